// Round 4
// baseline (595.943 us; speedup 1.0000x reference)
//
#include <hip/hip_runtime.h>
#include <hip/hip_bf16.h>
#include <math.h>
#include <stdint.h>

typedef __bf16 bf16;
typedef __bf16 bf16x4 __attribute__((ext_vector_type(4)));
typedef __bf16 bf16x8 __attribute__((ext_vector_type(8)));
typedef float f32x4 __attribute__((ext_vector_type(4)));

#define D_MODEL 2048
#define SEQ     2048
#define NHEADS  16
#define DH      128

// async 16B global -> LDS (wave-uniform LDS base + lane*16)
__device__ __forceinline__ void async_copy16(const bf16* g, bf16* l) {
    typedef const unsigned int __attribute__((address_space(1))) gu32;
    typedef unsigned int __attribute__((address_space(3))) lu32;
    __builtin_amdgcn_global_load_lds((gu32*)g, (lu32*)(unsigned int)(unsigned long long)(l),
                                     16, 0, 0);
}

// ---------------------------------------------------------------------------
// Pre-pass: x fp32 -> bf16 (row-major, unchanged layout)
// ---------------------------------------------------------------------------
__global__ __launch_bounds__(256)
void convert_x_kernel(const float* __restrict__ x, bf16* __restrict__ xb)
{
    int i = blockIdx.x * 256 + threadIdx.x;   // 2M float4 chunks
    float4 v = ((const float4*)x)[i];
    bf16x4 o;
    o[0] = (bf16)v.x; o[1] = (bf16)v.y; o[2] = (bf16)v.z; o[3] = (bf16)v.w;
    ((bf16x4*)xb)[i] = o;
}

// ---------------------------------------------------------------------------
// Pre-pass: W [k][n] fp32 -> WT [n][k] bf16, z selects Wq/Wk/Wv/Wo
// ---------------------------------------------------------------------------
__global__ __launch_bounds__(256)
void transpose_w_kernel(const float* __restrict__ Wq, const float* __restrict__ Wk,
                        const float* __restrict__ Wv, const float* __restrict__ Wo,
                        bf16* __restrict__ WTbase)
{
    const int z = blockIdx.z;
    const float* __restrict__ W = (z == 0) ? Wq : (z == 1) ? Wk : (z == 2) ? Wv : Wo;
    bf16* __restrict__ Wt = WTbase + (size_t)z * (D_MODEL * D_MODEL);
    const int n0 = blockIdx.x * 64, k0 = blockIdx.y * 64;
    const int tid = threadIdx.x;
    __shared__ bf16 Tl[64][68];   // [n][k]

#pragma unroll
    for (int i = 0; i < 4; ++i) {
        int idx = tid + i * 256;
        int kr = idx >> 4, nc = (idx & 15) * 4;
        float4 w = *(const float4*)&W[(size_t)(k0 + kr) * D_MODEL + n0 + nc];
        Tl[nc + 0][kr] = (bf16)w.x;
        Tl[nc + 1][kr] = (bf16)w.y;
        Tl[nc + 2][kr] = (bf16)w.z;
        Tl[nc + 3][kr] = (bf16)w.w;
    }
    __syncthreads();
#pragma unroll
    for (int i = 0; i < 4; ++i) {
        int idx = tid + i * 256;
        int nr = idx >> 4, kc = (idx & 15) * 4;
        *(bf16x4*)&Wt[(size_t)(n0 + nr) * D_MODEL + k0 + kc] = *(const bf16x4*)&Tl[nr][kc];
    }
}

// ---------------------------------------------------------------------------
// Pre-pass (after qkv): vout fp32 [bh][s][128] -> vT bf16 [bh][128][s]
// ---------------------------------------------------------------------------
__global__ __launch_bounds__(256)
void transpose_v_kernel(const float* __restrict__ V, bf16* __restrict__ Vt)
{
    const int s0 = blockIdx.x * 64, d0 = blockIdx.y * 64, bh = blockIdx.z;
    const float* __restrict__ Vb = V + (size_t)bh * SEQ * DH;
    bf16* __restrict__ Vtb = Vt + (size_t)bh * DH * SEQ;
    const int tid = threadIdx.x;
    __shared__ bf16 Tl[64][68];   // [d][s]

#pragma unroll
    for (int i = 0; i < 4; ++i) {
        int idx = tid + i * 256;
        int sr = idx >> 4, dc = (idx & 15) * 4;
        float4 v = *(const float4*)&Vb[(size_t)(s0 + sr) * DH + d0 + dc];
        Tl[dc + 0][sr] = (bf16)v.x;
        Tl[dc + 1][sr] = (bf16)v.y;
        Tl[dc + 2][sr] = (bf16)v.z;
        Tl[dc + 3][sr] = (bf16)v.w;
    }
    __syncthreads();
#pragma unroll
    for (int i = 0; i < 4; ++i) {
        int idx = tid + i * 256;
        int dr = idx >> 4, sc = (idx & 15) * 4;
        *(bf16x4*)&Vtb[(size_t)(d0 + dr) * SEQ + s0 + sc] = *(const bf16x4*)&Tl[dr][sc];
    }
}

// ---------------------------------------------------------------------------
// 128x256 bf16 GEMM core, BK=64, 8 waves (2M x 4N), wave tile 64x64.
// 2 phases per K-tile, counted-vmcnt pipeline (T3+T4+T5):
//   q0: ds-read A(mt 0,1) + all B || stage A(t+1)->p^1 ; bar; lgkm0; 16 MFMA; bar
//   q1: ds-read A(mt 2,3)        || stage B(t+2)->p   ; bar; lgkm0; 16 MFMA;
//       vmcnt(4); bar
// Invariant at q1 vmcnt(4): outstanding = {B(t+1)x4, A(t+1)x2, B(t+2)x4};
// drain leaves only B(t+2) -> everything needed at (t+1,q0) has landed.
// LDS 96 KiB: 2 parities x (A 16K + B 32K), fragment-ordered (conflict-free),
// frag = 1 KiB = 16 rows x 32 k-half, addr = frag*512 + lane*8 (bf16 elems).
// Per-thread global src pointers precomputed; per call add scalar kt*64.
// ---------------------------------------------------------------------------
__device__ __forceinline__ void gemm128x256_core(const bf16* __restrict__ A,
                                                 const bf16* __restrict__ Bt,
                                                 int bm, int bn,
                                                 bf16* lds,
                                                 f32x4 acc[4][4])
{
    const int tid = threadIdx.x;
    const int wave = tid >> 6, lane = tid & 63, quad = lane >> 4, l16 = lane & 15;
    const int wr = wave >> 2, wc = wave & 3;

    // precomputed per-thread src pointers (tile 0) and LDS element offsets
    const bf16* pA[2]; int dA[2];
#pragma unroll
    for (int j = 0; j < 2; ++j) {
        const int f = j * 8 + wave;            // 16 A-frags
        pA[j] = A + (size_t)(bm * 128 + (f >> 1) * 16 + l16) * D_MODEL + (f & 1) * 32 + quad * 8;
        dA[j] = f * 512 + lane * 8;
    }
    const bf16* pB[4]; int dB[4];
#pragma unroll
    for (int i = 0; i < 4; ++i) {
        const int f = (i >> 1) * 16 + (i & 1) * 8 + wave;   // 32 B-frags
        pB[i] = Bt + (size_t)(bn * 256 + (f >> 1) * 16 + l16) * D_MODEL + (f & 1) * 32 + quad * 8;
        dB[i] = f * 512 + lane * 8;
    }

    auto stA = [&](int p, int kt) {
#pragma unroll
        for (int j = 0; j < 2; ++j)
            async_copy16(pA[j] + kt * 64, lds + p * 24576 + dA[j]);
    };
    auto stB = [&](int p, int kt, int h) {
#pragma unroll
        for (int j = 0; j < 2; ++j)
            async_copy16(pB[h * 2 + j] + kt * 64, lds + p * 24576 + 8192 + dB[h * 2 + j]);
    };

    // prologue: A(0)x2, B(0)x4, B(1)x4 = 10 outstanding; drain to B(1)x4
    stA(0, 0); stB(0, 0, 0); stB(0, 0, 1); stB(1, 1, 0); stB(1, 1, 1);
    asm volatile("s_waitcnt vmcnt(4)" ::: "memory");
    __builtin_amdgcn_s_barrier();

    for (int t = 0; t < 32; ++t) {
        const int p = t & 1;
        const bf16* Ab = lds + p * 24576;
        const bf16* Bb = Ab + 8192;
        const int tn1 = (t + 1 < 31) ? t + 1 : 31;
        const int tn2 = (t + 2 < 31) ? t + 2 : 31;

        bf16x8 bfr[4][2], af[2][2];

        // ---- phase q0: A row-groups 0,1 x all B ----
#pragma unroll
        for (int mi = 0; mi < 2; ++mi)
#pragma unroll
            for (int kk = 0; kk < 2; ++kk)
                af[mi][kk] = *(const bf16x8*)(Ab + ((wr * 4 + mi) * 2 + kk) * 512 + lane * 8);
#pragma unroll
        for (int n = 0; n < 4; ++n)
#pragma unroll
            for (int kk = 0; kk < 2; ++kk)
                bfr[n][kk] = *(const bf16x8*)(Bb + ((wc * 4 + n) * 2 + kk) * 512 + lane * 8);
        stA(p ^ 1, tn1);
        __builtin_amdgcn_s_barrier();
        asm volatile("s_waitcnt lgkmcnt(0)" ::: "memory");
        __builtin_amdgcn_sched_barrier(0);
        __builtin_amdgcn_s_setprio(1);
#pragma unroll
        for (int mi = 0; mi < 2; ++mi)
#pragma unroll
            for (int n = 0; n < 4; ++n)
#pragma unroll
                for (int kk = 0; kk < 2; ++kk)
                    acc[mi][n] = __builtin_amdgcn_mfma_f32_16x16x32_bf16(
                        af[mi][kk], bfr[n][kk], acc[mi][n], 0, 0, 0);
        __builtin_amdgcn_s_setprio(0);
        __builtin_amdgcn_s_barrier();

        // ---- phase q1: A row-groups 2,3 x all B ----
#pragma unroll
        for (int mi = 0; mi < 2; ++mi)
#pragma unroll
            for (int kk = 0; kk < 2; ++kk)
                af[mi][kk] = *(const bf16x8*)(Ab + ((wr * 4 + 2 + mi) * 2 + kk) * 512 + lane * 8);
        stB(p, tn2, 0); stB(p, tn2, 1);
        __builtin_amdgcn_s_barrier();
        asm volatile("s_waitcnt lgkmcnt(0)" ::: "memory");
        __builtin_amdgcn_sched_barrier(0);
        __builtin_amdgcn_s_setprio(1);
#pragma unroll
        for (int mi = 0; mi < 2; ++mi)
#pragma unroll
            for (int n = 0; n < 4; ++n)
#pragma unroll
                for (int kk = 0; kk < 2; ++kk)
                    acc[2 + mi][n] = __builtin_amdgcn_mfma_f32_16x16x32_bf16(
                        af[mi][kk], bfr[n][kk], acc[2 + mi][n], 0, 0, 0);
        __builtin_amdgcn_s_setprio(0);
        asm volatile("s_waitcnt vmcnt(4)" ::: "memory");
        __builtin_amdgcn_s_barrier();
    }
    asm volatile("s_waitcnt vmcnt(0)" ::: "memory");
}

// ---------------------------------------------------------------------------
// Fused QKV projection GEMM: A [4096][2048] x WT rows 0..6143 ([q;k;v]).
// 768 blocks (32 bm x 24 bn) = exactly 3 blocks/CU. z = bn>>3.
//   z=0: q bf16 (ws); z=1: k fp32 (d_out) + bf16 copy (ws); z=2: v fp32.
// ---------------------------------------------------------------------------
__global__ __launch_bounds__(512, 2)
void gemm_qkv_kernel(const bf16* __restrict__ A, const bf16* __restrict__ WT,
                     const float* __restrict__ bq, const float* __restrict__ bk,
                     const float* __restrict__ bv,
                     bf16* __restrict__ qout, float* __restrict__ kout,
                     bf16* __restrict__ kb16, float* __restrict__ vout)
{
    __shared__ bf16 lds[49152];
    // XCD swizzle: 768 = 8 x 96; per XCD: bn-major chunks (B panel L2-resident)
    const int id = blockIdx.x;
    const int swz = (id & 7) * 96 + (id >> 3);
    const int bm = swz & 31, bn = swz >> 5;

    f32x4 acc[4][4] = {};
    gemm128x256_core(A, WT, bm, bn, lds, acc);

    const int tid = threadIdx.x;
    const int wave = tid >> 6, lane = tid & 63, quad = lane >> 4, l16 = lane & 15;
    const int wr = wave >> 2, wc = wave & 3;
    const int z = bn >> 3;
    const float* __restrict__ bias = (z == 0) ? bq : (z == 1) ? bk : bv;

#pragma unroll
    for (int a = 0; a < 4; ++a) {
#pragma unroll
        for (int n = 0; n < 4; ++n) {
#pragma unroll
            for (int r = 0; r < 4; ++r) {
                int m  = bm * 128 + wr * 64 + a * 16 + quad * 4 + r;
                int nl = (bn & 7) * 256 + wc * 64 + n * 16 + l16;
                float val = acc[a][n][r] + bias[nl];
                int b = m >> 11, s = m & (SEQ - 1);
                int h = nl >> 7, dh = nl & (DH - 1);
                size_t off = ((size_t)(b * NHEADS + h) * SEQ + s) * DH + dh;
                if (z == 0) {
                    qout[off] = (bf16)val;
                } else if (z == 1) {
                    kout[off] = val;
                    kb16[off] = (bf16)val;
                } else {
                    vout[off] = val;
                }
            }
        }
    }
}

// ---------------------------------------------------------------------------
// Output projection GEMM: attn_out = ctx @ Wo + bo (fp32 out [4096][2048]).
// 256 blocks (32 bm x 8 bn) = exactly 1 block/CU.
// ---------------------------------------------------------------------------
__global__ __launch_bounds__(512, 2)
void gemm_out_kernel(const bf16* __restrict__ A, const bf16* __restrict__ Bt,
                     const float* __restrict__ bias, float* __restrict__ out)
{
    __shared__ bf16 lds[49152];
    const int id = blockIdx.x;
    const int swz = (id & 7) * 32 + (id >> 3);   // 256 = 8 x 32
    const int bm = swz & 31, bn = swz >> 5;

    f32x4 acc[4][4] = {};
    gemm128x256_core(A, Bt, bm, bn, lds, acc);

    const int tid = threadIdx.x;
    const int wave = tid >> 6, lane = tid & 63, quad = lane >> 4, l16 = lane & 15;
    const int wr = wave >> 2, wc = wave & 3;

#pragma unroll
    for (int a = 0; a < 4; ++a) {
#pragma unroll
        for (int n = 0; n < 4; ++n) {
#pragma unroll
            for (int r = 0; r < 4; ++r) {
                int m  = bm * 128 + wr * 64 + a * 16 + quad * 4 + r;
                int nn = bn * 256 + wc * 64 + n * 16 + l16;
                out[(size_t)m * D_MODEL + nn] = acc[a][n][r] + bias[nn];
            }
        }
    }
}

// ---------------------------------------------------------------------------
// Flash attention (causal). One block per (64-row q tile, bh).
// Q,K bf16 [bh][s][128]; Vt bf16 [bh][128][s]; ctx bf16 [b][s][h*128+d].
// Unpadded XOR-swizzled LDS (40960 B -> 4 blocks/CU), Q frags from global,
// K/V staged via global_load_lds with pre-swizzled source, balanced remap.
// ---------------------------------------------------------------------------
__global__ __launch_bounds__(256, 4)
void attn_kernel(const bf16* __restrict__ Q, const bf16* __restrict__ K,
                 const bf16* __restrict__ Vt, bf16* __restrict__ ctx)
{
    // balanced remap: ids 0..511 -> qb 31..16 (heavy), 512..1023 -> qb 0..15
    const int id = blockIdx.x;
    const int p  = id & 511;
    const int bh = p >> 4;          // 0..31
    const int j  = p & 15;
    const int qb = (id >> 9) ? j : (31 - j);

    const int tid = threadIdx.x;
    const int wave = tid >> 6, lane = tid & 63, quad = lane >> 4, l16 = lane & 15;

    __shared__ bf16 Ks[64 * 128];    // 16 KB, row stride 256 B
    __shared__ bf16 VsT[128 * 64];   // 16 KB, row stride 128 B ([d][key])
    __shared__ bf16 Ps[4 * 16 * 64]; //  8 KB, per-wave [16][64], stride 128 B
    char* const ksb = (char*)Ks;
    char* const vsb = (char*)VsT;
    char* const psb = (char*)Ps + wave * 2048;

    // Q fragments straight from global (one-time, row-strided 16B loads)
    const bf16* qsrc = Q + ((size_t)bh * SEQ + (size_t)qb * 64 + wave * 16 + l16) * DH;
    bf16x8 qf[4];
#pragma unroll
    for (int dd = 0; dd < 4; ++dd)
        qf[dd] = *(const bf16x8*)&qsrc[dd * 32 + quad * 8];

    f32x4 o[8] = {};
    float m_i[4], l_i[4];
#pragma unroll
    for (int r = 0; r < 4; ++r) { m_i[r] = -INFINITY; l_i[r] = 0.f; }

    const float scale = 0.08838834764831845f;  // 1/sqrt(128)
    const bf16* ksrc0 = K + (size_t)bh * SEQ * DH;
    const bf16* vsrc0 = Vt + (size_t)bh * DH * SEQ;

    for (int kb = 0; kb <= qb; ++kb) {
        __syncthreads();   // previous iteration's K/V reads done

        // stage K tile (64 x 128): linear LDS dest, pre-swizzled global src
        {
            const char* kg = (const char*)(ksrc0 + (size_t)(kb * 64) * DH);
#pragma unroll
            for (int i = 0; i < 4; ++i) {
                int seg = i * 4 + wave;            // 16 segs x 1 KB
                int row = seg * 4 + (lane >> 4);   // 0..63
                int colb = (lane & 15) * 16;       // physical col byte
                const char* src = kg + row * 256 + (colb ^ ((row & 7) << 4));
                async_copy16((const bf16*)src, (bf16*)(ksb + seg * 1024));
            }
            // stage Vt tile (128 d-rows x 64 keys)
            const char* vg = (const char*)(vsrc0 + kb * 64);
#pragma unroll
            for (int i = 0; i < 4; ++i) {
                int seg = i * 4 + wave;
                int d = seg * 8 + (lane >> 3);     // 0..127
                int colb = (lane & 7) * 16;
                const char* src = vg + (size_t)d * (SEQ * 2) + (colb ^ ((d & 7) << 4));
                async_copy16((const bf16*)src, (bf16*)(vsb + seg * 1024));
            }
        }
        __syncthreads();

        // S = Q K^T (16 rows x 64 keys per wave)
        float pvals[4][4];
#pragma unroll
        for (int t = 0; t < 4; ++t) {
            f32x4 s = {};
            const int row = t * 16 + l16;
            const int swz = (row & 7) << 4;
#pragma unroll
            for (int dd = 0; dd < 4; ++dd) {
                bf16x8 b = *(const bf16x8*)(ksb + row * 256 + ((dd * 64 + quad * 16) ^ swz));
                s = __builtin_amdgcn_mfma_f32_16x16x32_bf16(qf[dd], b, s, 0, 0, 0);
            }
#pragma unroll
            for (int r = 0; r < 4; ++r) pvals[t][r] = s[r];
        }

        const bool diag = (kb == qb);
#pragma unroll
        for (int r = 0; r < 4; ++r) {
            int qrow = qb * 64 + wave * 16 + quad * 4 + r;
            float mx = -INFINITY;
#pragma unroll
            for (int t = 0; t < 4; ++t) {
                float s = pvals[t][r] * scale;
                int kcol = kb * 64 + t * 16 + l16;
                if (diag && kcol > qrow) s = -INFINITY;
                pvals[t][r] = s;
                mx = fmaxf(mx, s);
            }
#pragma unroll
            for (int off = 1; off < 16; off <<= 1)
                mx = fmaxf(mx, __shfl_xor(mx, off, 64));
            float mnew = fmaxf(m_i[r], mx);
            float alpha = __expf(m_i[r] - mnew);
            m_i[r] = mnew;
            float rs = 0.f;
#pragma unroll
            for (int t = 0; t < 4; ++t) {
                float pexp = __expf(pvals[t][r] - mnew);
                pvals[t][r] = pexp;
                rs += pexp;
            }
#pragma unroll
            for (int off = 1; off < 16; off <<= 1)
                rs += __shfl_xor(rs, off, 64);
            l_i[r] = l_i[r] * alpha + rs;
#pragma unroll
            for (int dt = 0; dt < 8; ++dt) o[dt][r] *= alpha;
        }

        // P -> LDS (C-layout -> A-layout), wave-local, swizzled
#pragma unroll
        for (int t = 0; t < 4; ++t)
#pragma unroll
            for (int r = 0; r < 4; ++r) {
                int row = quad * 4 + r;
                *(bf16*)(psb + row * 128 + (((t * 16 + l16) * 2) ^ ((row & 7) << 4))) =
                    (bf16)pvals[t][r];
            }

        // O += P @ V  (swizzled b-fragments from VsT)
        bf16x8 pa[2];
#pragma unroll
        for (int kk2 = 0; kk2 < 2; ++kk2)
            pa[kk2] = *(const bf16x8*)(psb + l16 * 128 +
                                       ((kk2 * 64 + quad * 16) ^ ((l16 & 7) << 4)));
#pragma unroll
        for (int dt = 0; dt < 8; ++dt) {
            const int row = dt * 16 + l16;
            const int swz = (row & 7) << 4;
#pragma unroll
            for (int kk2 = 0; kk2 < 2; ++kk2) {
                bf16x8 b = *(const bf16x8*)(vsb + row * 128 + ((kk2 * 64 + quad * 16) ^ swz));
                o[dt] = __builtin_amdgcn_mfma_f32_16x16x32_bf16(pa[kk2], b, o[dt], 0, 0, 0);
            }
        }
    }

    // epilogue
    const int b = bh >> 4, h = bh & (NHEADS - 1);
    float inv_l[4];
#pragma unroll
    for (int r = 0; r < 4; ++r) inv_l[r] = 1.0f / l_i[r];
#pragma unroll
    for (int dt = 0; dt < 8; ++dt) {
#pragma unroll
        for (int r = 0; r < 4; ++r) {
            int s = qb * 64 + wave * 16 + quad * 4 + r;
            int d = dt * 16 + l16;
            ctx[((size_t)(b * SEQ + s)) * D_MODEL + h * DH + d] = (bf16)(o[dt][r] * inv_l[r]);
        }
    }
}

// ---------------------------------------------------------------------------
// Residual + LayerNorm: one block per row
// ---------------------------------------------------------------------------
__global__ __launch_bounds__(256)
void ln_kernel(const float* __restrict__ attn, const float* __restrict__ x,
               const float* __restrict__ gamma, const float* __restrict__ beta,
               float* __restrict__ ln)
{
    const int row = blockIdx.x;
    const int tid = threadIdx.x;
    const int wave = tid >> 6, lane = tid & 63;
    const float* a  = attn + (size_t)row * D_MODEL;
    const float* xr = x    + (size_t)row * D_MODEL;

    float4 y4[2];
    float sum = 0.f, sumsq = 0.f;
#pragma unroll
    for (int i = 0; i < 2; ++i) {
        int c = (tid + i * 256) * 4;
        float4 av = *(const float4*)&a[c];
        float4 xv = *(const float4*)&xr[c];
        float4 y;
        y.x = av.x + xv.x; y.y = av.y + xv.y; y.z = av.z + xv.z; y.w = av.w + xv.w;
        y4[i] = y;
        sum   += y.x + y.y + y.z + y.w;
        sumsq += y.x * y.x + y.y * y.y + y.z * y.z + y.w * y.w;
    }
#pragma unroll
    for (int off = 1; off < 64; off <<= 1) {
        sum   += __shfl_xor(sum, off, 64);
        sumsq += __shfl_xor(sumsq, off, 64);
    }
    __shared__ float rsum[4], rsumsq[4];
    if (lane == 0) { rsum[wave] = sum; rsumsq[wave] = sumsq; }
    __syncthreads();
    float tot = 0.f, tot2 = 0.f;
#pragma unroll
    for (int i = 0; i < 4; ++i) { tot += rsum[i]; tot2 += rsumsq[i]; }
    const float mu  = tot * (1.0f / D_MODEL);
    const float var = tot2 * (1.0f / D_MODEL) - mu * mu;
    const float rstd = rsqrtf(var + 1e-5f);

#pragma unroll
    for (int i = 0; i < 2; ++i) {
        int c = (tid + i * 256) * 4;
        float4 gv = *(const float4*)&gamma[c];
        float4 bv = *(const float4*)&beta[c];
        float4 y = y4[i];
        float4 r;
        r.x = gv.x * (y.x - mu) * rstd + bv.x;
        r.y = gv.y * (y.y - mu) * rstd + bv.y;
        r.z = gv.z * (y.z - mu) * rstd + bv.z;
        r.w = gv.w * (y.w - mu) * rstd + bv.w;
        *(float4*)&ln[(size_t)row * D_MODEL + c] = r;
    }
}

// ---------------------------------------------------------------------------
extern "C" void kernel_launch(void* const* d_in, const int* in_sizes, int n_in,
                              void* d_out, int out_size, void* d_ws, size_t ws_size,
                              hipStream_t stream)
{
    const float* x     = (const float*)d_in[0];
    const float* Wq    = (const float*)d_in[1];
    const float* bq    = (const float*)d_in[2];
    const float* Wk    = (const float*)d_in[3];
    const float* bk    = (const float*)d_in[4];
    const float* Wv    = (const float*)d_in[5];
    const float* bv    = (const float*)d_in[6];
    const float* Wo    = (const float*)d_in[7];
    const float* bo    = (const float*)d_in[8];
    const float* gamma = (const float*)d_in[9];
    const float* beta  = (const float*)d_in[10];

    float* out      = (float*)d_out;
    float* ln       = out;                 // [B,S,D]
    float* attn_out = out + 8388608;       // [B,S,D]
    float* kout     = out + 16777216;      // [B,H,S,Dh]
    float* vout     = out + 25165824;      // [B,H,S,Dh]

    // workspace layout (bf16 elements)
    bf16* wsb  = (bf16*)d_ws;
    bf16* xb   = wsb;                        // [4096][2048]            8M
    bf16* WT   = wsb + 8388608;              // 4x [2048][2048] (q,k,v,o) 16M
    bf16* qws  = wsb + 25165824;             // [bh][s][128]            8M
    bf16* kb16 = wsb + 33554432;             // [bh][s][128]            8M
    bf16* vT   = wsb + 41943040;             // [bh][128][s]            8M
    bf16* ctx  = wsb + 50331648;             // [4096][2048]            8M

    convert_x_kernel<<<8192, 256, 0, stream>>>(x, xb);
    transpose_w_kernel<<<dim3(32, 32, 4), 256, 0, stream>>>(Wq, Wk, Wv, Wo, WT);
    gemm_qkv_kernel<<<dim3(768), 512, 0, stream>>>(xb, WT, bq, bk, bv,
                                                    qws, kout, kb16, vout);
    transpose_v_kernel<<<dim3(32, 2, 32), 256, 0, stream>>>(vout, vT);
    attn_kernel<<<dim3(1024), 256, 0, stream>>>(qws, kb16, vT, ctx);
    gemm_out_kernel<<<dim3(256), 512, 0, stream>>>(ctx, WT + 3 * (size_t)(D_MODEL * D_MODEL),
                                                    bo, attn_out);
    ln_kernel<<<4096, 256, 0, stream>>>(attn_out, x, gamma, beta, ln);
}

// Round 5
// 566.056 us; speedup vs baseline: 1.0528x; 1.0528x over previous
//
#include <hip/hip_runtime.h>
#include <hip/hip_bf16.h>
#include <math.h>
#include <stdint.h>

typedef __bf16 bf16;
typedef __bf16 bf16x4 __attribute__((ext_vector_type(4)));
typedef __bf16 bf16x8 __attribute__((ext_vector_type(8)));
typedef float f32x4 __attribute__((ext_vector_type(4)));

#define D_MODEL 2048
#define SEQ     2048
#define NHEADS  16
#define DH      128

// async 16B global -> LDS (wave-uniform LDS base + lane*16)
__device__ __forceinline__ void async_copy16(const bf16* g, bf16* l) {
    typedef const unsigned int __attribute__((address_space(1))) gu32;
    typedef unsigned int __attribute__((address_space(3))) lu32;
    __builtin_amdgcn_global_load_lds((gu32*)g, (lu32*)(unsigned int)(unsigned long long)(l),
                                     16, 0, 0);
}

// ---------------------------------------------------------------------------
// Pre-pass: x fp32 -> bf16 (row-major, unchanged layout)
// ---------------------------------------------------------------------------
__global__ __launch_bounds__(256)
void convert_x_kernel(const float* __restrict__ x, bf16* __restrict__ xb)
{
    int i = blockIdx.x * 256 + threadIdx.x;   // 2M float4 chunks
    float4 v = ((const float4*)x)[i];
    bf16x4 o;
    o[0] = (bf16)v.x; o[1] = (bf16)v.y; o[2] = (bf16)v.z; o[3] = (bf16)v.w;
    ((bf16x4*)xb)[i] = o;
}

// ---------------------------------------------------------------------------
// Pre-pass: W [k][n] fp32 -> WT [n][k] bf16, z selects Wq/Wk/Wv/Wo
// ---------------------------------------------------------------------------
__global__ __launch_bounds__(256)
void transpose_w_kernel(const float* __restrict__ Wq, const float* __restrict__ Wk,
                        const float* __restrict__ Wv, const float* __restrict__ Wo,
                        bf16* __restrict__ WTbase)
{
    const int z = blockIdx.z;
    const float* __restrict__ W = (z == 0) ? Wq : (z == 1) ? Wk : (z == 2) ? Wv : Wo;
    bf16* __restrict__ Wt = WTbase + (size_t)z * (D_MODEL * D_MODEL);
    const int n0 = blockIdx.x * 64, k0 = blockIdx.y * 64;
    const int tid = threadIdx.x;
    __shared__ bf16 Tl[64][68];   // [n][k]

#pragma unroll
    for (int i = 0; i < 4; ++i) {
        int idx = tid + i * 256;
        int kr = idx >> 4, nc = (idx & 15) * 4;
        float4 w = *(const float4*)&W[(size_t)(k0 + kr) * D_MODEL + n0 + nc];
        Tl[nc + 0][kr] = (bf16)w.x;
        Tl[nc + 1][kr] = (bf16)w.y;
        Tl[nc + 2][kr] = (bf16)w.z;
        Tl[nc + 3][kr] = (bf16)w.w;
    }
    __syncthreads();
#pragma unroll
    for (int i = 0; i < 4; ++i) {
        int idx = tid + i * 256;
        int nr = idx >> 4, kc = (idx & 15) * 4;
        *(bf16x4*)&Wt[(size_t)(n0 + nr) * D_MODEL + k0 + kc] = *(const bf16x4*)&Tl[nr][kc];
    }
}

// ---------------------------------------------------------------------------
// Pre-pass (after qkv): vout fp32 [bh][s][128] -> vT bf16 [bh][128][s]
// ---------------------------------------------------------------------------
__global__ __launch_bounds__(256)
void transpose_v_kernel(const float* __restrict__ V, bf16* __restrict__ Vt)
{
    const int s0 = blockIdx.x * 64, d0 = blockIdx.y * 64, bh = blockIdx.z;
    const float* __restrict__ Vb = V + (size_t)bh * SEQ * DH;
    bf16* __restrict__ Vtb = Vt + (size_t)bh * DH * SEQ;
    const int tid = threadIdx.x;
    __shared__ bf16 Tl[64][68];   // [d][s]

#pragma unroll
    for (int i = 0; i < 4; ++i) {
        int idx = tid + i * 256;
        int sr = idx >> 4, dc = (idx & 15) * 4;
        float4 v = *(const float4*)&Vb[(size_t)(s0 + sr) * DH + d0 + dc];
        Tl[dc + 0][sr] = (bf16)v.x;
        Tl[dc + 1][sr] = (bf16)v.y;
        Tl[dc + 2][sr] = (bf16)v.z;
        Tl[dc + 3][sr] = (bf16)v.w;
    }
    __syncthreads();
#pragma unroll
    for (int i = 0; i < 4; ++i) {
        int idx = tid + i * 256;
        int dr = idx >> 4, sc = (idx & 15) * 4;
        *(bf16x4*)&Vtb[(size_t)(d0 + dr) * SEQ + s0 + sc] = *(const bf16x4*)&Tl[dr][sc];
    }
}

// ---------------------------------------------------------------------------
// 256x192 bf16 GEMM core, BK=64, 8 waves (2M x 4N), wave tile 128x48.
// 4 phases per K-tile, counted-vmcnt pipeline (T3+T4+T5). Per wave per K-tile:
// 7 loads {q0: A(t+1)h0 x2, q1: A(t+1)h1 x2 + B(t+2)p0, q2: B(t+2)p1,
// q3: B(t+2)p2}, vmcnt(3) after q3 MFMA leaves exactly B(t+2)x3 in flight and
// drains A(t+1)+B(t+1). Prologue issues 10 (A0 x4, B0 x3, B1 x3) -> vmcnt(3).
// Clamped tail stages write dead regions; counts unchanged.
// LDS 112 KiB: 2 parities x (A 32K + B 24K), fragment-ordered (conflict-free),
// frag = 1 KiB = 16 rows x 32 k-half, addr = frag*512 + lane*8 (bf16 elems).
// ---------------------------------------------------------------------------
__device__ __forceinline__ void gemm256x192_core(const bf16* __restrict__ A,
                                                 const bf16* __restrict__ Bt,
                                                 int bm, int bn,
                                                 bf16* lds,
                                                 f32x4 acc[8][3])
{
    const int tid = threadIdx.x;
    const int wave = tid >> 6, lane = tid & 63, quad = lane >> 4, l16 = lane & 15;
    const int wr = wave >> 2, wc = wave & 3;

    // per-thread global src pointers (K-tile 0) and LDS element offsets
    const bf16* pA[4]; int dA[4];
#pragma unroll
    for (int h = 0; h < 2; ++h)
#pragma unroll
        for (int j = 0; j < 2; ++j) {
            const int f = h * 16 + j * 8 + wave;   // 32 A-frags
            pA[h * 2 + j] = A + (size_t)(bm * 256 + (f >> 1) * 16 + l16) * D_MODEL
                              + (f & 1) * 32 + quad * 8;
            dA[h * 2 + j] = f * 512 + lane * 8;
        }
    const bf16* pB[3]; int dB[3];
#pragma unroll
    for (int part = 0; part < 3; ++part) {
        const int f = part * 8 + wave;             // 24 B-frags
        pB[part] = Bt + (size_t)(bn * 192 + (f >> 1) * 16 + l16) * D_MODEL
                      + (f & 1) * 32 + quad * 8;
        dB[part] = 16384 + f * 512 + lane * 8;
    }

    auto stA = [&](int p, int kt, int h) {
#pragma unroll
        for (int j = 0; j < 2; ++j)
            async_copy16(pA[h * 2 + j] + kt * 64, lds + p * 28672 + dA[h * 2 + j]);
    };
    auto stB = [&](int p, int kt, int part) {
        async_copy16(pB[part] + kt * 64, lds + p * 28672 + dB[part]);
    };

    // prologue: A(0) x4, B(0) x3, B(1) x3 = 10 outstanding; drain to B(1) x3
    stA(0, 0, 0); stA(0, 0, 1);
    stB(0, 0, 0); stB(0, 0, 1); stB(0, 0, 2);
    stB(1, 1, 0); stB(1, 1, 1); stB(1, 1, 2);
    asm volatile("s_waitcnt vmcnt(3)" ::: "memory");
    __builtin_amdgcn_s_barrier();

    for (int t = 0; t < 32; ++t) {
        const int p = t & 1;
        const bf16* Ab = lds + p * 28672;
        const bf16* Bb = Ab + 16384;
        const int tn1 = (t + 1 < 31) ? t + 1 : 31;
        const int tn2 = (t + 2 < 31) ? t + 2 : 31;
        bf16x8 bfr[3][2];
#pragma unroll
        for (int q = 0; q < 4; ++q) {
            bf16x8 af[2][2];
#pragma unroll
            for (int mi = 0; mi < 2; ++mi)
#pragma unroll
                for (int kk = 0; kk < 2; ++kk) {
                    const int mt = wr * 8 + 2 * q + mi;
                    af[mi][kk] = *(const bf16x8*)(Ab + (mt * 2 + kk) * 512 + lane * 8);
                }
            if (q == 0) {
#pragma unroll
                for (int n = 0; n < 3; ++n)
#pragma unroll
                    for (int kk = 0; kk < 2; ++kk) {
                        const int nt = wc * 3 + n;
                        bfr[n][kk] = *(const bf16x8*)(Bb + (nt * 2 + kk) * 512 + lane * 8);
                    }
                stA(p ^ 1, tn1, 0);
            } else if (q == 1) {
                stA(p ^ 1, tn1, 1);
                stB(p, tn2, 0);
            } else if (q == 2) {
                stB(p, tn2, 1);
            } else {
                stB(p, tn2, 2);
            }

            __builtin_amdgcn_s_barrier();
            asm volatile("s_waitcnt lgkmcnt(0)" ::: "memory");
            __builtin_amdgcn_sched_barrier(0);
            __builtin_amdgcn_s_setprio(1);
#pragma unroll
            for (int mi = 0; mi < 2; ++mi)
#pragma unroll
                for (int n = 0; n < 3; ++n)
#pragma unroll
                    for (int kk = 0; kk < 2; ++kk)
                        acc[2 * q + mi][n] = __builtin_amdgcn_mfma_f32_16x16x32_bf16(
                            af[mi][kk], bfr[n][kk], acc[2 * q + mi][n], 0, 0, 0);
            __builtin_amdgcn_s_setprio(0);
            if (q == 3) asm volatile("s_waitcnt vmcnt(3)" ::: "memory");
            __builtin_amdgcn_s_barrier();
        }
    }
    asm volatile("s_waitcnt vmcnt(0)" ::: "memory");
}

// ---------------------------------------------------------------------------
// 256x256 bf16 GEMM core (round-3, measured-good), BK=64, 8 waves (2M x 4N),
// 4 phases/K-tile, vmcnt(4) once per K-tile. LDS 128 KiB.
// ---------------------------------------------------------------------------
__device__ __forceinline__ void gemm256_core(const bf16* __restrict__ A,
                                             const bf16* __restrict__ Bt,
                                             int bm, int bn,
                                             bf16* lds,
                                             f32x4 acc[8][4])
{
    const int tid = threadIdx.x;
    const int wave = tid >> 6, lane = tid & 63, quad = lane >> 4, l16 = lane & 15;
    const int wr = wave >> 2, wc = wave & 3;
    const int rowA = bm * 256, rowB = bn * 256;

    auto stageA = [&](int p, int kt, int h) {
#pragma unroll
        for (int j = 0; j < 2; ++j) {
            const int f = h * 16 + j * 8 + wave;
            const int mt = f >> 1, kk = f & 1;
            const bf16* g = &A[(size_t)(rowA + mt * 16 + l16) * D_MODEL + kt * 64 + kk * 32 + quad * 8];
            async_copy16(g, lds + p * 32768 + f * 512 + lane * 8);
        }
    };
    auto stageB = [&](int p, int kt, int h) {
#pragma unroll
        for (int j = 0; j < 2; ++j) {
            const int f = h * 16 + j * 8 + wave;
            const int nt = f >> 1, kk = f & 1;
            const bf16* g = &Bt[(size_t)(rowB + nt * 16 + l16) * D_MODEL + kt * 64 + kk * 32 + quad * 8];
            async_copy16(g, lds + p * 32768 + 16384 + f * 512 + lane * 8);
        }
    };

    // prologue: A(0) h0,h1 ; B(0) h0,h1 ; B(1) h0,h1  (12 loads/wave)
    stageA(0, 0, 0); stageA(0, 0, 1);
    stageB(0, 0, 0); stageB(0, 0, 1);
    stageB(1, 1, 0); stageB(1, 1, 1);
    asm volatile("s_waitcnt vmcnt(4)" ::: "memory");
    __builtin_amdgcn_s_barrier();

    for (int t = 0; t < 32; ++t) {
        const int p = t & 1;
        const bf16* Ab = lds + p * 32768;
        const bf16* Bb = Ab + 16384;
        const int tn1 = (t + 1 < 31) ? t + 1 : 31;
        const int tn2 = (t + 2 < 31) ? t + 2 : 31;
        bf16x8 bfr[4][2];
#pragma unroll
        for (int q = 0; q < 4; ++q) {
            bf16x8 af[2][2];
#pragma unroll
            for (int mi = 0; mi < 2; ++mi)
#pragma unroll
                for (int kk = 0; kk < 2; ++kk) {
                    const int mt = wr * 8 + 2 * q + mi;
                    af[mi][kk] = *(const bf16x8*)(Ab + (mt * 2 + kk) * 512 + lane * 8);
                }
            if (q == 0) {
#pragma unroll
                for (int n = 0; n < 4; ++n)
#pragma unroll
                    for (int kk = 0; kk < 2; ++kk) {
                        const int nt = wc * 4 + n;
                        bfr[n][kk] = *(const bf16x8*)(Bb + (nt * 2 + kk) * 512 + lane * 8);
                    }
                stageA(p ^ 1, tn1, 0);
            } else if (q == 1) {
                stageA(p ^ 1, tn1, 1);
            } else if (q == 2) {
                stageB(p, tn2, 0);
            } else {
                stageB(p, tn2, 1);
            }

            __builtin_amdgcn_s_barrier();
            asm volatile("s_waitcnt lgkmcnt(0)" ::: "memory");
            __builtin_amdgcn_sched_barrier(0);
            __builtin_amdgcn_s_setprio(1);
#pragma unroll
            for (int mi = 0; mi < 2; ++mi)
#pragma unroll
                for (int n = 0; n < 4; ++n)
#pragma unroll
                    for (int kk = 0; kk < 2; ++kk)
                        acc[2 * q + mi][n] = __builtin_amdgcn_mfma_f32_16x16x32_bf16(
                            af[mi][kk], bfr[n][kk], acc[2 * q + mi][n], 0, 0, 0);
            __builtin_amdgcn_s_setprio(0);
            if (q == 3) asm volatile("s_waitcnt vmcnt(4)" ::: "memory");
            __builtin_amdgcn_s_barrier();
        }
    }
    asm volatile("s_waitcnt vmcnt(0)" ::: "memory");
}

// ---------------------------------------------------------------------------
// Fused QKV projection GEMM: A [4096][2048] x WT rows 0..6143 ([q;k;v]).
// 256x192 tiles -> grid 16 x 32 = 512 blocks = exactly 2 full rounds at
// 1 block/CU (fill 1.0; kills round-3's 1.5-round tail). A 192-col tile may
// straddle the q/k/v boundary; z resolved per 16-col fragment (16-aligned).
// ---------------------------------------------------------------------------
__global__ __launch_bounds__(512, 2)
void gemm_qkv_kernel(const bf16* __restrict__ A, const bf16* __restrict__ WT,
                     const float* __restrict__ bq, const float* __restrict__ bk,
                     const float* __restrict__ bv,
                     bf16* __restrict__ qout, float* __restrict__ kout,
                     bf16* __restrict__ kb16, float* __restrict__ vout)
{
    __shared__ bf16 lds[57344];
    // XCD swizzle: 512 = 8 x 64; per XCD 64 tiles = 2 bm x 32 bn (A L2-resident)
    const int id = blockIdx.x;
    const int swz = (id & 7) * 64 + (id >> 3);
    const int bm = swz >> 5, bn = swz & 31;

    f32x4 acc[8][3] = {};
    gemm256x192_core(A, WT, bm, bn, lds, acc);

    const int tid = threadIdx.x;
    const int wave = tid >> 6, lane = tid & 63, quad = lane >> 4, l16 = lane & 15;
    const int wr = wave >> 2, wc = wave & 3;

#pragma unroll
    for (int a = 0; a < 8; ++a) {
#pragma unroll
        for (int n = 0; n < 3; ++n) {
            const int col0 = bn * 192 + wc * 48 + n * 16;   // 16-aligned
            const int z = col0 >> 11;                        // frag-uniform
            const float* __restrict__ bias = (z == 0) ? bq : (z == 1) ? bk : bv;
            const int nl = (col0 & 2047) + l16;
            const int h = nl >> 7, dh = nl & (DH - 1);
#pragma unroll
            for (int r = 0; r < 4; ++r) {
                int m = bm * 256 + wr * 128 + a * 16 + quad * 4 + r;
                float val = acc[a][n][r] + bias[nl];
                int b = m >> 11, s = m & (SEQ - 1);
                size_t off = ((size_t)(b * NHEADS + h) * SEQ + s) * DH + dh;
                if (z == 0) {
                    qout[off] = (bf16)val;
                } else if (z == 1) {
                    kout[off] = val;
                    kb16[off] = (bf16)val;
                } else {
                    vout[off] = val;
                }
            }
        }
    }
}

// ---------------------------------------------------------------------------
// Output projection GEMM: attn_out = ctx @ Wo + bo (fp32 out [4096][2048]).
// Round-3 measured config: 256x256, 128 blocks.
// ---------------------------------------------------------------------------
__global__ __launch_bounds__(512, 2)
void gemm_out_kernel(const bf16* __restrict__ A, const bf16* __restrict__ Bt,
                     const float* __restrict__ bias, float* __restrict__ out)
{
    __shared__ bf16 lds[65536];
    const int id = blockIdx.x;          // 128 blocks, 16 per XCD
    const int swz = (id & 7) * 16 + (id >> 3);
    const int bm = swz >> 3, bn = swz & 7;

    f32x4 acc[8][4] = {};
    gemm256_core(A, Bt, bm, bn, lds, acc);

    const int tid = threadIdx.x;
    const int wave = tid >> 6, lane = tid & 63, quad = lane >> 4, l16 = lane & 15;
    const int wr = wave >> 2, wc = wave & 3;

#pragma unroll
    for (int mi = 0; mi < 8; ++mi) {
#pragma unroll
        for (int n = 0; n < 4; ++n) {
#pragma unroll
            for (int r = 0; r < 4; ++r) {
                int m = bm * 256 + wr * 128 + mi * 16 + quad * 4 + r;
                int nn = bn * 256 + wc * 64 + n * 16 + l16;
                out[(size_t)m * D_MODEL + nn] = acc[mi][n][r] + bias[nn];
            }
        }
    }
}

// ---------------------------------------------------------------------------
// Flash attention (causal). One block per (64-row q tile, bh).
// Q,K bf16 [bh][s][128]; Vt bf16 [bh][128][s]; ctx bf16 [b][s][h*128+d].
// Unpadded XOR-swizzled LDS (40960 B -> 4 blocks/CU), Q frags from global,
// K/V staged via global_load_lds with pre-swizzled source, balanced remap.
// ---------------------------------------------------------------------------
__global__ __launch_bounds__(256, 4)
void attn_kernel(const bf16* __restrict__ Q, const bf16* __restrict__ K,
                 const bf16* __restrict__ Vt, bf16* __restrict__ ctx)
{
    // balanced remap: ids 0..511 -> qb 31..16 (heavy), 512..1023 -> qb 0..15
    const int id = blockIdx.x;
    const int p  = id & 511;
    const int bh = p >> 4;          // 0..31
    const int j  = p & 15;
    const int qb = (id >> 9) ? j : (31 - j);

    const int tid = threadIdx.x;
    const int wave = tid >> 6, lane = tid & 63, quad = lane >> 4, l16 = lane & 15;

    __shared__ bf16 Ks[64 * 128];    // 16 KB, row stride 256 B
    __shared__ bf16 VsT[128 * 64];   // 16 KB, row stride 128 B ([d][key])
    __shared__ bf16 Ps[4 * 16 * 64]; //  8 KB, per-wave [16][64], stride 128 B
    char* const ksb = (char*)Ks;
    char* const vsb = (char*)VsT;
    char* const psb = (char*)Ps + wave * 2048;

    // Q fragments straight from global (one-time, row-strided 16B loads)
    const bf16* qsrc = Q + ((size_t)bh * SEQ + (size_t)qb * 64 + wave * 16 + l16) * DH;
    bf16x8 qf[4];
#pragma unroll
    for (int dd = 0; dd < 4; ++dd)
        qf[dd] = *(const bf16x8*)&qsrc[dd * 32 + quad * 8];

    f32x4 o[8] = {};
    float m_i[4], l_i[4];
#pragma unroll
    for (int r = 0; r < 4; ++r) { m_i[r] = -INFINITY; l_i[r] = 0.f; }

    const float scale = 0.08838834764831845f;  // 1/sqrt(128)
    const bf16* ksrc0 = K + (size_t)bh * SEQ * DH;
    const bf16* vsrc0 = Vt + (size_t)bh * DH * SEQ;

    for (int kb = 0; kb <= qb; ++kb) {
        __syncthreads();   // previous iteration's K/V reads done

        // stage K tile (64 x 128): linear LDS dest, pre-swizzled global src
        {
            const char* kg = (const char*)(ksrc0 + (size_t)(kb * 64) * DH);
#pragma unroll
            for (int i = 0; i < 4; ++i) {
                int seg = i * 4 + wave;            // 16 segs x 1 KB
                int row = seg * 4 + (lane >> 4);   // 0..63
                int colb = (lane & 15) * 16;       // physical col byte
                const char* src = kg + row * 256 + (colb ^ ((row & 7) << 4));
                async_copy16((const bf16*)src, (bf16*)(ksb + seg * 1024));
            }
            // stage Vt tile (128 d-rows x 64 keys)
            const char* vg = (const char*)(vsrc0 + kb * 64);
#pragma unroll
            for (int i = 0; i < 4; ++i) {
                int seg = i * 4 + wave;
                int d = seg * 8 + (lane >> 3);     // 0..127
                int colb = (lane & 7) * 16;
                const char* src = vg + (size_t)d * (SEQ * 2) + (colb ^ ((d & 7) << 4));
                async_copy16((const bf16*)src, (bf16*)(vsb + seg * 1024));
            }
        }
        __syncthreads();

        // S = Q K^T (16 rows x 64 keys per wave)
        float pvals[4][4];
#pragma unroll
        for (int t = 0; t < 4; ++t) {
            f32x4 s = {};
            const int row = t * 16 + l16;
            const int swz = (row & 7) << 4;
#pragma unroll
            for (int dd = 0; dd < 4; ++dd) {
                bf16x8 b = *(const bf16x8*)(ksb + row * 256 + ((dd * 64 + quad * 16) ^ swz));
                s = __builtin_amdgcn_mfma_f32_16x16x32_bf16(qf[dd], b, s, 0, 0, 0);
            }
#pragma unroll
            for (int r = 0; r < 4; ++r) pvals[t][r] = s[r];
        }

        const bool diag = (kb == qb);
#pragma unroll
        for (int r = 0; r < 4; ++r) {
            int qrow = qb * 64 + wave * 16 + quad * 4 + r;
            float mx = -INFINITY;
#pragma unroll
            for (int t = 0; t < 4; ++t) {
                float s = pvals[t][r] * scale;
                int kcol = kb * 64 + t * 16 + l16;
                if (diag && kcol > qrow) s = -INFINITY;
                pvals[t][r] = s;
                mx = fmaxf(mx, s);
            }
#pragma unroll
            for (int off = 1; off < 16; off <<= 1)
                mx = fmaxf(mx, __shfl_xor(mx, off, 64));
            float mnew = fmaxf(m_i[r], mx);
            float alpha = __expf(m_i[r] - mnew);
            m_i[r] = mnew;
            float rs = 0.f;
#pragma unroll
            for (int t = 0; t < 4; ++t) {
                float pexp = __expf(pvals[t][r] - mnew);
                pvals[t][r] = pexp;
                rs += pexp;
            }
#pragma unroll
            for (int off = 1; off < 16; off <<= 1)
                rs += __shfl_xor(rs, off, 64);
            l_i[r] = l_i[r] * alpha + rs;
#pragma unroll
            for (int dt = 0; dt < 8; ++dt) o[dt][r] *= alpha;
        }

        // P -> LDS (C-layout -> A-layout), wave-local, swizzled
#pragma unroll
        for (int t = 0; t < 4; ++t)
#pragma unroll
            for (int r = 0; r < 4; ++r) {
                int row = quad * 4 + r;
                *(bf16*)(psb + row * 128 + (((t * 16 + l16) * 2) ^ ((row & 7) << 4))) =
                    (bf16)pvals[t][r];
            }

        // O += P @ V  (swizzled b-fragments from VsT)
        bf16x8 pa[2];
#pragma unroll
        for (int kk2 = 0; kk2 < 2; ++kk2)
            pa[kk2] = *(const bf16x8*)(psb + l16 * 128 +
                                       ((kk2 * 64 + quad * 16) ^ ((l16 & 7) << 4)));
#pragma unroll
        for (int dt = 0; dt < 8; ++dt) {
            const int row = dt * 16 + l16;
            const int swz = (row & 7) << 4;
#pragma unroll
            for (int kk2 = 0; kk2 < 2; ++kk2) {
                bf16x8 b = *(const bf16x8*)(vsb + row * 128 + ((kk2 * 64 + quad * 16) ^ swz));
                o[dt] = __builtin_amdgcn_mfma_f32_16x16x32_bf16(pa[kk2], b, o[dt], 0, 0, 0);
            }
        }
    }

    // epilogue
    const int b = bh >> 4, h = bh & (NHEADS - 1);
    float inv_l[4];
#pragma unroll
    for (int r = 0; r < 4; ++r) inv_l[r] = 1.0f / l_i[r];
#pragma unroll
    for (int dt = 0; dt < 8; ++dt) {
#pragma unroll
        for (int r = 0; r < 4; ++r) {
            int s = qb * 64 + wave * 16 + quad * 4 + r;
            int d = dt * 16 + l16;
            ctx[((size_t)(b * SEQ + s)) * D_MODEL + h * DH + d] = (bf16)(o[dt][r] * inv_l[r]);
        }
    }
}

// ---------------------------------------------------------------------------
// Residual + LayerNorm: one block per row
// ---------------------------------------------------------------------------
__global__ __launch_bounds__(256)
void ln_kernel(const float* __restrict__ attn, const float* __restrict__ x,
               const float* __restrict__ gamma, const float* __restrict__ beta,
               float* __restrict__ ln)
{
    const int row = blockIdx.x;
    const int tid = threadIdx.x;
    const int wave = tid >> 6, lane = tid & 63;
    const float* a  = attn + (size_t)row * D_MODEL;
    const float* xr = x    + (size_t)row * D_MODEL;

    float4 y4[2];
    float sum = 0.f, sumsq = 0.f;
#pragma unroll
    for (int i = 0; i < 2; ++i) {
        int c = (tid + i * 256) * 4;
        float4 av = *(const float4*)&a[c];
        float4 xv = *(const float4*)&xr[c];
        float4 y;
        y.x = av.x + xv.x; y.y = av.y + xv.y; y.z = av.z + xv.z; y.w = av.w + xv.w;
        y4[i] = y;
        sum   += y.x + y.y + y.z + y.w;
        sumsq += y.x * y.x + y.y * y.y + y.z * y.z + y.w * y.w;
    }
#pragma unroll
    for (int off = 1; off < 64; off <<= 1) {
        sum   += __shfl_xor(sum, off, 64);
        sumsq += __shfl_xor(sumsq, off, 64);
    }
    __shared__ float rsum[4], rsumsq[4];
    if (lane == 0) { rsum[wave] = sum; rsumsq[wave] = sumsq; }
    __syncthreads();
    float tot = 0.f, tot2 = 0.f;
#pragma unroll
    for (int i = 0; i < 4; ++i) { tot += rsum[i]; tot2 += rsumsq[i]; }
    const float mu  = tot * (1.0f / D_MODEL);
    const float var = tot2 * (1.0f / D_MODEL) - mu * mu;
    const float rstd = rsqrtf(var + 1e-5f);

#pragma unroll
    for (int i = 0; i < 2; ++i) {
        int c = (tid + i * 256) * 4;
        float4 gv = *(const float4*)&gamma[c];
        float4 bv = *(const float4*)&beta[c];
        float4 y = y4[i];
        float4 r;
        r.x = gv.x * (y.x - mu) * rstd + bv.x;
        r.y = gv.y * (y.y - mu) * rstd + bv.y;
        r.z = gv.z * (y.z - mu) * rstd + bv.z;
        r.w = gv.w * (y.w - mu) * rstd + bv.w;
        *(float4*)&ln[(size_t)row * D_MODEL + c] = r;
    }
}

// ---------------------------------------------------------------------------
extern "C" void kernel_launch(void* const* d_in, const int* in_sizes, int n_in,
                              void* d_out, int out_size, void* d_ws, size_t ws_size,
                              hipStream_t stream)
{
    const float* x     = (const float*)d_in[0];
    const float* Wq    = (const float*)d_in[1];
    const float* bq    = (const float*)d_in[2];
    const float* Wk    = (const float*)d_in[3];
    const float* bk    = (const float*)d_in[4];
    const float* Wv    = (const float*)d_in[5];
    const float* bv    = (const float*)d_in[6];
    const float* Wo    = (const float*)d_in[7];
    const float* bo    = (const float*)d_in[8];
    const float* gamma = (const float*)d_in[9];
    const float* beta  = (const float*)d_in[10];

    float* out      = (float*)d_out;
    float* ln       = out;                 // [B,S,D]
    float* attn_out = out + 8388608;       // [B,S,D]
    float* kout     = out + 16777216;      // [B,H,S,Dh]
    float* vout     = out + 25165824;      // [B,H,S,Dh]

    // workspace layout (bf16 elements)
    bf16* wsb  = (bf16*)d_ws;
    bf16* xb   = wsb;                        // [4096][2048]            8M
    bf16* WT   = wsb + 8388608;              // 4x [2048][2048] (q,k,v,o) 16M
    bf16* qws  = wsb + 25165824;             // [bh][s][128]            8M
    bf16* kb16 = wsb + 33554432;             // [bh][s][128]            8M
    bf16* vT   = wsb + 41943040;             // [bh][128][s]            8M
    bf16* ctx  = wsb + 50331648;             // [4096][2048]            8M

    convert_x_kernel<<<8192, 256, 0, stream>>>(x, xb);
    transpose_w_kernel<<<dim3(32, 32, 4), 256, 0, stream>>>(Wq, Wk, Wv, Wo, WT);
    gemm_qkv_kernel<<<dim3(512), 512, 0, stream>>>(xb, WT, bq, bk, bv,
                                                    qws, kout, kb16, vout);
    transpose_v_kernel<<<dim3(32, 2, 32), 256, 0, stream>>>(vout, vT);
    attn_kernel<<<dim3(1024), 256, 0, stream>>>(qws, kb16, vT, ctx);
    gemm_out_kernel<<<dim3(128), 512, 0, stream>>>(ctx, WT + 3 * (size_t)(D_MODEL * D_MODEL),
                                                    bo, attn_out);
    ln_kernel<<<4096, 256, 0, stream>>>(attn_out, x, gamma, beta, ln);
}

// Round 6
// 557.590 us; speedup vs baseline: 1.0688x; 1.0152x over previous
//
#include <hip/hip_runtime.h>
#include <hip/hip_bf16.h>
#include <math.h>
#include <stdint.h>

typedef __bf16 bf16;
typedef __bf16 bf16x4 __attribute__((ext_vector_type(4)));
typedef __bf16 bf16x8 __attribute__((ext_vector_type(8)));
typedef float f32x4 __attribute__((ext_vector_type(4)));

#define D_MODEL 2048
#define SEQ     2048
#define NHEADS  16
#define DH      128

// async 16B global -> LDS (wave-uniform LDS base + lane*16)
__device__ __forceinline__ void async_copy16(const bf16* g, bf16* l) {
    typedef const unsigned int __attribute__((address_space(1))) gu32;
    typedef unsigned int __attribute__((address_space(3))) lu32;
    __builtin_amdgcn_global_load_lds((gu32*)g, (lu32*)(unsigned int)(unsigned long long)(l),
                                     16, 0, 0);
}

// ---------------------------------------------------------------------------
// Pre-pass: x fp32 -> bf16 (row-major, unchanged layout)
// ---------------------------------------------------------------------------
__global__ __launch_bounds__(256)
void convert_x_kernel(const float* __restrict__ x, bf16* __restrict__ xb)
{
    int i = blockIdx.x * 256 + threadIdx.x;   // 2M float4 chunks
    float4 v = ((const float4*)x)[i];
    bf16x4 o;
    o[0] = (bf16)v.x; o[1] = (bf16)v.y; o[2] = (bf16)v.z; o[3] = (bf16)v.w;
    ((bf16x4*)xb)[i] = o;
}

// ---------------------------------------------------------------------------
// Pre-pass: W [k][n] fp32 -> WT [n][k] bf16, z selects Wq/Wk/Wv/Wo
// ---------------------------------------------------------------------------
__global__ __launch_bounds__(256)
void transpose_w_kernel(const float* __restrict__ Wq, const float* __restrict__ Wk,
                        const float* __restrict__ Wv, const float* __restrict__ Wo,
                        bf16* __restrict__ WTbase)
{
    const int z = blockIdx.z;
    const float* __restrict__ W = (z == 0) ? Wq : (z == 1) ? Wk : (z == 2) ? Wv : Wo;
    bf16* __restrict__ Wt = WTbase + (size_t)z * (D_MODEL * D_MODEL);
    const int n0 = blockIdx.x * 64, k0 = blockIdx.y * 64;
    const int tid = threadIdx.x;
    __shared__ bf16 Tl[64][68];   // [n][k]

#pragma unroll
    for (int i = 0; i < 4; ++i) {
        int idx = tid + i * 256;
        int kr = idx >> 4, nc = (idx & 15) * 4;
        float4 w = *(const float4*)&W[(size_t)(k0 + kr) * D_MODEL + n0 + nc];
        Tl[nc + 0][kr] = (bf16)w.x;
        Tl[nc + 1][kr] = (bf16)w.y;
        Tl[nc + 2][kr] = (bf16)w.z;
        Tl[nc + 3][kr] = (bf16)w.w;
    }
    __syncthreads();
#pragma unroll
    for (int i = 0; i < 4; ++i) {
        int idx = tid + i * 256;
        int nr = idx >> 4, kc = (idx & 15) * 4;
        *(bf16x4*)&Wt[(size_t)(n0 + nr) * D_MODEL + k0 + kc] = *(const bf16x4*)&Tl[nr][kc];
    }
}

// ---------------------------------------------------------------------------
// 256x192 bf16 GEMM core, BK=64, 8 waves (2M x 4N), wave tile 128x48.
// 4 phases per K-tile, counted-vmcnt pipeline (T3+T4+T5). Per wave per K-tile:
// 7 loads {q0: A(t+1)h0 x2, q1: A(t+1)h1 x2 + B(t+2)p0, q2: B(t+2)p1,
// q3: B(t+2)p2}, vmcnt(3) after q3 MFMA leaves exactly B(t+2)x3 in flight and
// drains A(t+1)+B(t+1). Prologue issues 10 (A0 x4, B0 x3, B1 x3) -> vmcnt(3).
// Clamped tail stages write dead regions; counts unchanged.
// LDS 112 KiB: 2 parities x (A 32K + B 24K), fragment-ordered (conflict-free),
// frag = 1 KiB = 16 rows x 32 k-half, addr = frag*512 + lane*8 (bf16 elems).
// ---------------------------------------------------------------------------
__device__ __forceinline__ void gemm256x192_core(const bf16* __restrict__ A,
                                                 const bf16* __restrict__ Bt,
                                                 int bm, int bn,
                                                 bf16* lds,
                                                 f32x4 acc[8][3])
{
    const int tid = threadIdx.x;
    const int wave = tid >> 6, lane = tid & 63, quad = lane >> 4, l16 = lane & 15;
    const int wr = wave >> 2, wc = wave & 3;

    // per-thread global src pointers (K-tile 0) and LDS element offsets
    const bf16* pA[4]; int dA[4];
#pragma unroll
    for (int h = 0; h < 2; ++h)
#pragma unroll
        for (int j = 0; j < 2; ++j) {
            const int f = h * 16 + j * 8 + wave;   // 32 A-frags
            pA[h * 2 + j] = A + (size_t)(bm * 256 + (f >> 1) * 16 + l16) * D_MODEL
                              + (f & 1) * 32 + quad * 8;
            dA[h * 2 + j] = f * 512 + lane * 8;
        }
    const bf16* pB[3]; int dB[3];
#pragma unroll
    for (int part = 0; part < 3; ++part) {
        const int f = part * 8 + wave;             // 24 B-frags
        pB[part] = Bt + (size_t)(bn * 192 + (f >> 1) * 16 + l16) * D_MODEL
                      + (f & 1) * 32 + quad * 8;
        dB[part] = 16384 + f * 512 + lane * 8;
    }

    auto stA = [&](int p, int kt, int h) {
#pragma unroll
        for (int j = 0; j < 2; ++j)
            async_copy16(pA[h * 2 + j] + kt * 64, lds + p * 28672 + dA[h * 2 + j]);
    };
    auto stB = [&](int p, int kt, int part) {
        async_copy16(pB[part] + kt * 64, lds + p * 28672 + dB[part]);
    };

    // prologue: A(0) x4, B(0) x3, B(1) x3 = 10 outstanding; drain to B(1) x3
    stA(0, 0, 0); stA(0, 0, 1);
    stB(0, 0, 0); stB(0, 0, 1); stB(0, 0, 2);
    stB(1, 1, 0); stB(1, 1, 1); stB(1, 1, 2);
    asm volatile("s_waitcnt vmcnt(3)" ::: "memory");
    __builtin_amdgcn_s_barrier();

    for (int t = 0; t < 32; ++t) {
        const int p = t & 1;
        const bf16* Ab = lds + p * 28672;
        const bf16* Bb = Ab + 16384;
        const int tn1 = (t + 1 < 31) ? t + 1 : 31;
        const int tn2 = (t + 2 < 31) ? t + 2 : 31;
        bf16x8 bfr[3][2];
#pragma unroll
        for (int q = 0; q < 4; ++q) {
            bf16x8 af[2][2];
#pragma unroll
            for (int mi = 0; mi < 2; ++mi)
#pragma unroll
                for (int kk = 0; kk < 2; ++kk) {
                    const int mt = wr * 8 + 2 * q + mi;
                    af[mi][kk] = *(const bf16x8*)(Ab + (mt * 2 + kk) * 512 + lane * 8);
                }
            if (q == 0) {
#pragma unroll
                for (int n = 0; n < 3; ++n)
#pragma unroll
                    for (int kk = 0; kk < 2; ++kk) {
                        const int nt = wc * 3 + n;
                        bfr[n][kk] = *(const bf16x8*)(Bb + (nt * 2 + kk) * 512 + lane * 8);
                    }
                stA(p ^ 1, tn1, 0);
            } else if (q == 1) {
                stA(p ^ 1, tn1, 1);
                stB(p, tn2, 0);
            } else if (q == 2) {
                stB(p, tn2, 1);
            } else {
                stB(p, tn2, 2);
            }

            __builtin_amdgcn_s_barrier();
            asm volatile("s_waitcnt lgkmcnt(0)" ::: "memory");
            __builtin_amdgcn_sched_barrier(0);
            __builtin_amdgcn_s_setprio(1);
#pragma unroll
            for (int mi = 0; mi < 2; ++mi)
#pragma unroll
                for (int n = 0; n < 3; ++n)
#pragma unroll
                    for (int kk = 0; kk < 2; ++kk)
                        acc[2 * q + mi][n] = __builtin_amdgcn_mfma_f32_16x16x32_bf16(
                            af[mi][kk], bfr[n][kk], acc[2 * q + mi][n], 0, 0, 0);
            __builtin_amdgcn_s_setprio(0);
            if (q == 3) asm volatile("s_waitcnt vmcnt(3)" ::: "memory");
            __builtin_amdgcn_s_barrier();
        }
    }
    asm volatile("s_waitcnt vmcnt(0)" ::: "memory");
}

// ---------------------------------------------------------------------------
// 128x256 bf16 GEMM core (round-4, harness-verified), BK=64, 8 waves
// (2M x 4N), wave tile 64x64. 2 phases/K-tile, counted vmcnt(4).
// LDS 96 KiB: 2 parities x (A 16K + B 32K), fragment-ordered.
// ---------------------------------------------------------------------------
__device__ __forceinline__ void gemm128x256_core(const bf16* __restrict__ A,
                                                 const bf16* __restrict__ Bt,
                                                 int bm, int bn,
                                                 bf16* lds,
                                                 f32x4 acc[4][4])
{
    const int tid = threadIdx.x;
    const int wave = tid >> 6, lane = tid & 63, quad = lane >> 4, l16 = lane & 15;
    const int wr = wave >> 2, wc = wave & 3;

    // precomputed per-thread src pointers (tile 0) and LDS element offsets
    const bf16* pA[2]; int dA[2];
#pragma unroll
    for (int j = 0; j < 2; ++j) {
        const int f = j * 8 + wave;            // 16 A-frags
        pA[j] = A + (size_t)(bm * 128 + (f >> 1) * 16 + l16) * D_MODEL + (f & 1) * 32 + quad * 8;
        dA[j] = f * 512 + lane * 8;
    }
    const bf16* pB[4]; int dB[4];
#pragma unroll
    for (int i = 0; i < 4; ++i) {
        const int f = (i >> 1) * 16 + (i & 1) * 8 + wave;   // 32 B-frags
        pB[i] = Bt + (size_t)(bn * 256 + (f >> 1) * 16 + l16) * D_MODEL + (f & 1) * 32 + quad * 8;
        dB[i] = f * 512 + lane * 8;
    }

    auto stA = [&](int p, int kt) {
#pragma unroll
        for (int j = 0; j < 2; ++j)
            async_copy16(pA[j] + kt * 64, lds + p * 24576 + dA[j]);
    };
    auto stB = [&](int p, int kt, int h) {
#pragma unroll
        for (int j = 0; j < 2; ++j)
            async_copy16(pB[h * 2 + j] + kt * 64, lds + p * 24576 + 8192 + dB[h * 2 + j]);
    };

    // prologue: A(0)x2, B(0)x4, B(1)x4 = 10 outstanding; drain to B(1)x4
    stA(0, 0); stB(0, 0, 0); stB(0, 0, 1); stB(1, 1, 0); stB(1, 1, 1);
    asm volatile("s_waitcnt vmcnt(4)" ::: "memory");
    __builtin_amdgcn_s_barrier();

    for (int t = 0; t < 32; ++t) {
        const int p = t & 1;
        const bf16* Ab = lds + p * 24576;
        const bf16* Bb = Ab + 8192;
        const int tn1 = (t + 1 < 31) ? t + 1 : 31;
        const int tn2 = (t + 2 < 31) ? t + 2 : 31;

        bf16x8 bfr[4][2], af[2][2];

        // ---- phase q0: A row-groups 0,1 x all B ----
#pragma unroll
        for (int mi = 0; mi < 2; ++mi)
#pragma unroll
            for (int kk = 0; kk < 2; ++kk)
                af[mi][kk] = *(const bf16x8*)(Ab + ((wr * 4 + mi) * 2 + kk) * 512 + lane * 8);
#pragma unroll
        for (int n = 0; n < 4; ++n)
#pragma unroll
            for (int kk = 0; kk < 2; ++kk)
                bfr[n][kk] = *(const bf16x8*)(Bb + ((wc * 4 + n) * 2 + kk) * 512 + lane * 8);
        stA(p ^ 1, tn1);
        __builtin_amdgcn_s_barrier();
        asm volatile("s_waitcnt lgkmcnt(0)" ::: "memory");
        __builtin_amdgcn_sched_barrier(0);
        __builtin_amdgcn_s_setprio(1);
#pragma unroll
        for (int mi = 0; mi < 2; ++mi)
#pragma unroll
            for (int n = 0; n < 4; ++n)
#pragma unroll
                for (int kk = 0; kk < 2; ++kk)
                    acc[mi][n] = __builtin_amdgcn_mfma_f32_16x16x32_bf16(
                        af[mi][kk], bfr[n][kk], acc[mi][n], 0, 0, 0);
        __builtin_amdgcn_s_setprio(0);
        __builtin_amdgcn_s_barrier();

        // ---- phase q1: A row-groups 2,3 x all B ----
#pragma unroll
        for (int mi = 0; mi < 2; ++mi)
#pragma unroll
            for (int kk = 0; kk < 2; ++kk)
                af[mi][kk] = *(const bf16x8*)(Ab + ((wr * 4 + 2 + mi) * 2 + kk) * 512 + lane * 8);
        stB(p, tn2, 0); stB(p, tn2, 1);
        __builtin_amdgcn_s_barrier();
        asm volatile("s_waitcnt lgkmcnt(0)" ::: "memory");
        __builtin_amdgcn_sched_barrier(0);
        __builtin_amdgcn_s_setprio(1);
#pragma unroll
        for (int mi = 0; mi < 2; ++mi)
#pragma unroll
            for (int n = 0; n < 4; ++n)
#pragma unroll
                for (int kk = 0; kk < 2; ++kk)
                    acc[2 + mi][n] = __builtin_amdgcn_mfma_f32_16x16x32_bf16(
                        af[mi][kk], bfr[n][kk], acc[2 + mi][n], 0, 0, 0);
        __builtin_amdgcn_s_setprio(0);
        asm volatile("s_waitcnt vmcnt(4)" ::: "memory");
        __builtin_amdgcn_s_barrier();
    }
    asm volatile("s_waitcnt vmcnt(0)" ::: "memory");
}

// ---------------------------------------------------------------------------
// Fused QKV projection GEMM: A [4096][2048] x WT rows 0..6143 ([q;k;v]).
// 256x192 tiles -> grid 512 blocks = exactly 2 full rounds (fill 1.0).
// z resolved per 16-col fragment. z==2 additionally emits the transposed
// bf16 V copy (vT [bh][d][s]) as aligned 8B stores -> transpose_v pass gone.
// ---------------------------------------------------------------------------
__global__ __launch_bounds__(512, 2)
void gemm_qkv_kernel(const bf16* __restrict__ A, const bf16* __restrict__ WT,
                     const float* __restrict__ bq, const float* __restrict__ bk,
                     const float* __restrict__ bv,
                     bf16* __restrict__ qout, float* __restrict__ kout,
                     bf16* __restrict__ kb16, float* __restrict__ vout,
                     bf16* __restrict__ vtout)
{
    __shared__ bf16 lds[57344];
    // XCD swizzle: 512 = 8 x 64; per XCD 64 tiles = 2 bm x 32 bn (A L2-resident)
    const int id = blockIdx.x;
    const int swz = (id & 7) * 64 + (id >> 3);
    const int bm = swz >> 5, bn = swz & 31;

    f32x4 acc[8][3] = {};
    gemm256x192_core(A, WT, bm, bn, lds, acc);

    const int tid = threadIdx.x;
    const int wave = tid >> 6, lane = tid & 63, quad = lane >> 4, l16 = lane & 15;
    const int wr = wave >> 2, wc = wave & 3;

#pragma unroll
    for (int a = 0; a < 8; ++a) {
#pragma unroll
        for (int n = 0; n < 3; ++n) {
            const int col0 = bn * 192 + wc * 48 + n * 16;   // 16-aligned
            const int z = col0 >> 11;                        // frag-uniform
            const float* __restrict__ bias = (z == 0) ? bq : (z == 1) ? bk : bv;
            const int nl = (col0 & 2047) + l16;
            const int h = nl >> 7, dh = nl & (DH - 1);
            const int m0 = bm * 256 + wr * 128 + a * 16 + quad * 4;
            const int b0 = m0 >> 11, s0 = m0 & (SEQ - 1);
            bf16x4 vt4;
#pragma unroll
            for (int r = 0; r < 4; ++r) {
                int m = m0 + r;
                float val = acc[a][n][r] + bias[nl];
                int b = m >> 11, s = m & (SEQ - 1);
                size_t off = ((size_t)(b * NHEADS + h) * SEQ + s) * DH + dh;
                if (z == 0) {
                    qout[off] = (bf16)val;
                } else if (z == 1) {
                    kout[off] = val;
                    kb16[off] = (bf16)val;
                } else {
                    vout[off] = val;
                    vt4[r] = (bf16)val;
                }
            }
            if (z == 2) {
                // vT [bh][dh][s]: 4 consecutive s -> one aligned 8B store
                size_t voff = ((size_t)(b0 * NHEADS + h) * DH + dh) * SEQ + s0;
                *(bf16x4*)&vtout[voff] = vt4;
            }
        }
    }
}

// ---------------------------------------------------------------------------
// Output projection GEMM: attn_out = ctx @ Wo + bo (fp32 out [4096][2048]).
// 128x256 tiles -> 256 blocks (32 bm x 8 bn) = exactly 1 block/CU (fill 1.0,
// vs round-3/5's 128 blocks = 0.5 fill with half the machine idle).
// ---------------------------------------------------------------------------
__global__ __launch_bounds__(512, 2)
void gemm_out_kernel(const bf16* __restrict__ A, const bf16* __restrict__ Bt,
                     const float* __restrict__ bias, float* __restrict__ out)
{
    __shared__ bf16 lds[49152];
    const int id = blockIdx.x;
    const int swz = (id & 7) * 32 + (id >> 3);   // 256 = 8 x 32
    const int bm = swz & 31, bn = swz >> 5;

    f32x4 acc[4][4] = {};
    gemm128x256_core(A, Bt, bm, bn, lds, acc);

    const int tid = threadIdx.x;
    const int wave = tid >> 6, lane = tid & 63, quad = lane >> 4, l16 = lane & 15;
    const int wr = wave >> 2, wc = wave & 3;

#pragma unroll
    for (int a = 0; a < 4; ++a) {
#pragma unroll
        for (int n = 0; n < 4; ++n) {
#pragma unroll
            for (int r = 0; r < 4; ++r) {
                int m  = bm * 128 + wr * 64 + a * 16 + quad * 4 + r;
                int nn = bn * 256 + wc * 64 + n * 16 + l16;
                out[(size_t)m * D_MODEL + nn] = acc[a][n][r] + bias[nn];
            }
        }
    }
}

// ---------------------------------------------------------------------------
// Flash attention (causal). One block per (64-row q tile, bh).
// Q,K bf16 [bh][s][128]; Vt bf16 [bh][128][s]; ctx bf16 [b][s][h*128+d].
// Unpadded XOR-swizzled LDS (40960 B -> 4 blocks/CU), Q frags from global,
// K/V staged via global_load_lds with pre-swizzled source, balanced remap.
// ---------------------------------------------------------------------------
__global__ __launch_bounds__(256, 4)
void attn_kernel(const bf16* __restrict__ Q, const bf16* __restrict__ K,
                 const bf16* __restrict__ Vt, bf16* __restrict__ ctx)
{
    // balanced remap: ids 0..511 -> qb 31..16 (heavy), 512..1023 -> qb 0..15
    const int id = blockIdx.x;
    const int p  = id & 511;
    const int bh = p >> 4;          // 0..31
    const int j  = p & 15;
    const int qb = (id >> 9) ? j : (31 - j);

    const int tid = threadIdx.x;
    const int wave = tid >> 6, lane = tid & 63, quad = lane >> 4, l16 = lane & 15;

    __shared__ bf16 Ks[64 * 128];    // 16 KB, row stride 256 B
    __shared__ bf16 VsT[128 * 64];   // 16 KB, row stride 128 B ([d][key])
    __shared__ bf16 Ps[4 * 16 * 64]; //  8 KB, per-wave [16][64], stride 128 B
    char* const ksb = (char*)Ks;
    char* const vsb = (char*)VsT;
    char* const psb = (char*)Ps + wave * 2048;

    // Q fragments straight from global (one-time, row-strided 16B loads)
    const bf16* qsrc = Q + ((size_t)bh * SEQ + (size_t)qb * 64 + wave * 16 + l16) * DH;
    bf16x8 qf[4];
#pragma unroll
    for (int dd = 0; dd < 4; ++dd)
        qf[dd] = *(const bf16x8*)&qsrc[dd * 32 + quad * 8];

    f32x4 o[8] = {};
    float m_i[4], l_i[4];
#pragma unroll
    for (int r = 0; r < 4; ++r) { m_i[r] = -INFINITY; l_i[r] = 0.f; }

    const float scale = 0.08838834764831845f;  // 1/sqrt(128)
    const bf16* ksrc0 = K + (size_t)bh * SEQ * DH;
    const bf16* vsrc0 = Vt + (size_t)bh * DH * SEQ;

    for (int kb = 0; kb <= qb; ++kb) {
        __syncthreads();   // previous iteration's K/V reads done

        // stage K tile (64 x 128): linear LDS dest, pre-swizzled global src
        {
            const char* kg = (const char*)(ksrc0 + (size_t)(kb * 64) * DH);
#pragma unroll
            for (int i = 0; i < 4; ++i) {
                int seg = i * 4 + wave;            // 16 segs x 1 KB
                int row = seg * 4 + (lane >> 4);   // 0..63
                int colb = (lane & 15) * 16;       // physical col byte
                const char* src = kg + row * 256 + (colb ^ ((row & 7) << 4));
                async_copy16((const bf16*)src, (bf16*)(ksb + seg * 1024));
            }
            // stage Vt tile (128 d-rows x 64 keys)
            const char* vg = (const char*)(vsrc0 + kb * 64);
#pragma unroll
            for (int i = 0; i < 4; ++i) {
                int seg = i * 4 + wave;
                int d = seg * 8 + (lane >> 3);     // 0..127
                int colb = (lane & 7) * 16;
                const char* src = vg + (size_t)d * (SEQ * 2) + (colb ^ ((d & 7) << 4));
                async_copy16((const bf16*)src, (bf16*)(vsb + seg * 1024));
            }
        }
        __syncthreads();

        // S = Q K^T (16 rows x 64 keys per wave)
        float pvals[4][4];
#pragma unroll
        for (int t = 0; t < 4; ++t) {
            f32x4 s = {};
            const int row = t * 16 + l16;
            const int swz = (row & 7) << 4;
#pragma unroll
            for (int dd = 0; dd < 4; ++dd) {
                bf16x8 b = *(const bf16x8*)(ksb + row * 256 + ((dd * 64 + quad * 16) ^ swz));
                s = __builtin_amdgcn_mfma_f32_16x16x32_bf16(qf[dd], b, s, 0, 0, 0);
            }
#pragma unroll
            for (int r = 0; r < 4; ++r) pvals[t][r] = s[r];
        }

        const bool diag = (kb == qb);
#pragma unroll
        for (int r = 0; r < 4; ++r) {
            int qrow = qb * 64 + wave * 16 + quad * 4 + r;
            float mx = -INFINITY;
#pragma unroll
            for (int t = 0; t < 4; ++t) {
                float s = pvals[t][r] * scale;
                int kcol = kb * 64 + t * 16 + l16;
                if (diag && kcol > qrow) s = -INFINITY;
                pvals[t][r] = s;
                mx = fmaxf(mx, s);
            }
#pragma unroll
            for (int off = 1; off < 16; off <<= 1)
                mx = fmaxf(mx, __shfl_xor(mx, off, 64));
            float mnew = fmaxf(m_i[r], mx);
            float alpha = __expf(m_i[r] - mnew);
            m_i[r] = mnew;
            float rs = 0.f;
#pragma unroll
            for (int t = 0; t < 4; ++t) {
                float pexp = __expf(pvals[t][r] - mnew);
                pvals[t][r] = pexp;
                rs += pexp;
            }
#pragma unroll
            for (int off = 1; off < 16; off <<= 1)
                rs += __shfl_xor(rs, off, 64);
            l_i[r] = l_i[r] * alpha + rs;
#pragma unroll
            for (int dt = 0; dt < 8; ++dt) o[dt][r] *= alpha;
        }

        // P -> LDS (C-layout -> A-layout), wave-local, swizzled
#pragma unroll
        for (int t = 0; t < 4; ++t)
#pragma unroll
            for (int r = 0; r < 4; ++r) {
                int row = quad * 4 + r;
                *(bf16*)(psb + row * 128 + (((t * 16 + l16) * 2) ^ ((row & 7) << 4))) =
                    (bf16)pvals[t][r];
            }

        // O += P @ V  (swizzled b-fragments from VsT)
        bf16x8 pa[2];
#pragma unroll
        for (int kk2 = 0; kk2 < 2; ++kk2)
            pa[kk2] = *(const bf16x8*)(psb + l16 * 128 +
                                       ((kk2 * 64 + quad * 16) ^ ((l16 & 7) << 4)));
#pragma unroll
        for (int dt = 0; dt < 8; ++dt) {
            const int row = dt * 16 + l16;
            const int swz = (row & 7) << 4;
#pragma unroll
            for (int kk2 = 0; kk2 < 2; ++kk2) {
                bf16x8 b = *(const bf16x8*)(vsb + row * 128 + ((kk2 * 64 + quad * 16) ^ swz));
                o[dt] = __builtin_amdgcn_mfma_f32_16x16x32_bf16(pa[kk2], b, o[dt], 0, 0, 0);
            }
        }
    }

    // epilogue
    const int b = bh >> 4, h = bh & (NHEADS - 1);
    float inv_l[4];
#pragma unroll
    for (int r = 0; r < 4; ++r) inv_l[r] = 1.0f / l_i[r];
#pragma unroll
    for (int dt = 0; dt < 8; ++dt) {
#pragma unroll
        for (int r = 0; r < 4; ++r) {
            int s = qb * 64 + wave * 16 + quad * 4 + r;
            int d = dt * 16 + l16;
            ctx[((size_t)(b * SEQ + s)) * D_MODEL + h * DH + d] = (bf16)(o[dt][r] * inv_l[r]);
        }
    }
}

// ---------------------------------------------------------------------------
// Residual + LayerNorm: one block per row
// ---------------------------------------------------------------------------
__global__ __launch_bounds__(256)
void ln_kernel(const float* __restrict__ attn, const float* __restrict__ x,
               const float* __restrict__ gamma, const float* __restrict__ beta,
               float* __restrict__ ln)
{
    const int row = blockIdx.x;
    const int tid = threadIdx.x;
    const int wave = tid >> 6, lane = tid & 63;
    const float* a  = attn + (size_t)row * D_MODEL;
    const float* xr = x    + (size_t)row * D_MODEL;

    float4 y4[2];
    float sum = 0.f, sumsq = 0.f;
#pragma unroll
    for (int i = 0; i < 2; ++i) {
        int c = (tid + i * 256) * 4;
        float4 av = *(const float4*)&a[c];
        float4 xv = *(const float4*)&xr[c];
        float4 y;
        y.x = av.x + xv.x; y.y = av.y + xv.y; y.z = av.z + xv.z; y.w = av.w + xv.w;
        y4[i] = y;
        sum   += y.x + y.y + y.z + y.w;
        sumsq += y.x * y.x + y.y * y.y + y.z * y.z + y.w * y.w;
    }
#pragma unroll
    for (int off = 1; off < 64; off <<= 1) {
        sum   += __shfl_xor(sum, off, 64);
        sumsq += __shfl_xor(sumsq, off, 64);
    }
    __shared__ float rsum[4], rsumsq[4];
    if (lane == 0) { rsum[wave] = sum; rsumsq[wave] = sumsq; }
    __syncthreads();
    float tot = 0.f, tot2 = 0.f;
#pragma unroll
    for (int i = 0; i < 4; ++i) { tot += rsum[i]; tot2 += rsumsq[i]; }
    const float mu  = tot * (1.0f / D_MODEL);
    const float var = tot2 * (1.0f / D_MODEL) - mu * mu;
    const float rstd = rsqrtf(var + 1e-5f);

#pragma unroll
    for (int i = 0; i < 2; ++i) {
        int c = (tid + i * 256) * 4;
        float4 gv = *(const float4*)&gamma[c];
        float4 bv = *(const float4*)&beta[c];
        float4 y = y4[i];
        float4 r;
        r.x = gv.x * (y.x - mu) * rstd + bv.x;
        r.y = gv.y * (y.y - mu) * rstd + bv.y;
        r.z = gv.z * (y.z - mu) * rstd + bv.z;
        r.w = gv.w * (y.w - mu) * rstd + bv.w;
        *(float4*)&ln[(size_t)row * D_MODEL + c] = r;
    }
}

// ---------------------------------------------------------------------------
extern "C" void kernel_launch(void* const* d_in, const int* in_sizes, int n_in,
                              void* d_out, int out_size, void* d_ws, size_t ws_size,
                              hipStream_t stream)
{
    const float* x     = (const float*)d_in[0];
    const float* Wq    = (const float*)d_in[1];
    const float* bq    = (const float*)d_in[2];
    const float* Wk    = (const float*)d_in[3];
    const float* bk    = (const float*)d_in[4];
    const float* Wv    = (const float*)d_in[5];
    const float* bv    = (const float*)d_in[6];
    const float* Wo    = (const float*)d_in[7];
    const float* bo    = (const float*)d_in[8];
    const float* gamma = (const float*)d_in[9];
    const float* beta  = (const float*)d_in[10];

    float* out      = (float*)d_out;
    float* ln       = out;                 // [B,S,D]
    float* attn_out = out + 8388608;       // [B,S,D]
    float* kout     = out + 16777216;      // [B,H,S,Dh]
    float* vout     = out + 25165824;      // [B,H,S,Dh]

    // workspace layout (bf16 elements)
    bf16* wsb  = (bf16*)d_ws;
    bf16* xb   = wsb;                        // [4096][2048]            8M
    bf16* WT   = wsb + 8388608;              // 4x [2048][2048] (q,k,v,o) 16M
    bf16* qws  = wsb + 25165824;             // [bh][s][128]            8M
    bf16* kb16 = wsb + 33554432;             // [bh][s][128]            8M
    bf16* vT   = wsb + 41943040;             // [bh][128][s]            8M
    bf16* ctx  = wsb + 50331648;             // [4096][2048]            8M

    convert_x_kernel<<<8192, 256, 0, stream>>>(x, xb);
    transpose_w_kernel<<<dim3(32, 32, 4), 256, 0, stream>>>(Wq, Wk, Wv, Wo, WT);
    gemm_qkv_kernel<<<dim3(512), 512, 0, stream>>>(xb, WT, bq, bk, bv,
                                                    qws, kout, kb16, vout, vT);
    attn_kernel<<<dim3(1024), 256, 0, stream>>>(qws, kb16, vT, ctx);
    gemm_out_kernel<<<dim3(256), 512, 0, stream>>>(ctx, WT + 3 * (size_t)(D_MODEL * D_MODEL),
                                                    bo, attn_out);
    ln_kernel<<<4096, 256, 0, stream>>>(attn_out, x, gamma, beta, ln);
}

// Round 7
// 522.546 us; speedup vs baseline: 1.1405x; 1.0671x over previous
//
#include <hip/hip_runtime.h>
#include <hip/hip_bf16.h>
#include <math.h>
#include <stdint.h>

typedef __bf16 bf16;
typedef __bf16 bf16x4 __attribute__((ext_vector_type(4)));
typedef __bf16 bf16x8 __attribute__((ext_vector_type(8)));
typedef float f32x4 __attribute__((ext_vector_type(4)));

#define D_MODEL 2048
#define SEQ     2048
#define NHEADS  16
#define DH      128

// async 16B global -> LDS (wave-uniform LDS base + lane*16)
__device__ __forceinline__ void async_copy16(const bf16* g, bf16* l) {
    typedef const unsigned int __attribute__((address_space(1))) gu32;
    typedef unsigned int __attribute__((address_space(3))) lu32;
    __builtin_amdgcn_global_load_lds((gu32*)g, (lu32*)(unsigned int)(unsigned long long)(l),
                                     16, 0, 0);
}

// ---------------------------------------------------------------------------
// Pre-pass: x fp32 -> bf16 (row-major, unchanged layout)
// ---------------------------------------------------------------------------
__global__ __launch_bounds__(256)
void convert_x_kernel(const float* __restrict__ x, bf16* __restrict__ xb)
{
    int i = blockIdx.x * 256 + threadIdx.x;   // 2M float4 chunks
    float4 v = ((const float4*)x)[i];
    bf16x4 o;
    o[0] = (bf16)v.x; o[1] = (bf16)v.y; o[2] = (bf16)v.z; o[3] = (bf16)v.w;
    ((bf16x4*)xb)[i] = o;
}

// ---------------------------------------------------------------------------
// Pre-pass: W [k][n] fp32 -> WT [n][k] bf16, z selects Wq/Wk/Wv/Wo
// ---------------------------------------------------------------------------
__global__ __launch_bounds__(256)
void transpose_w_kernel(const float* __restrict__ Wq, const float* __restrict__ Wk,
                        const float* __restrict__ Wv, const float* __restrict__ Wo,
                        bf16* __restrict__ WTbase)
{
    const int z = blockIdx.z;
    const float* __restrict__ W = (z == 0) ? Wq : (z == 1) ? Wk : (z == 2) ? Wv : Wo;
    bf16* __restrict__ Wt = WTbase + (size_t)z * (D_MODEL * D_MODEL);
    const int n0 = blockIdx.x * 64, k0 = blockIdx.y * 64;
    const int tid = threadIdx.x;
    __shared__ bf16 Tl[64][68];   // [n][k]

#pragma unroll
    for (int i = 0; i < 4; ++i) {
        int idx = tid + i * 256;
        int kr = idx >> 4, nc = (idx & 15) * 4;
        float4 w = *(const float4*)&W[(size_t)(k0 + kr) * D_MODEL + n0 + nc];
        Tl[nc + 0][kr] = (bf16)w.x;
        Tl[nc + 1][kr] = (bf16)w.y;
        Tl[nc + 2][kr] = (bf16)w.z;
        Tl[nc + 3][kr] = (bf16)w.w;
    }
    __syncthreads();
#pragma unroll
    for (int i = 0; i < 4; ++i) {
        int idx = tid + i * 256;
        int nr = idx >> 4, kc = (idx & 15) * 4;
        *(bf16x4*)&Wt[(size_t)(n0 + nr) * D_MODEL + k0 + kc] = *(const bf16x4*)&Tl[nr][kc];
    }
}

// ---------------------------------------------------------------------------
// 256x192 bf16 GEMM core, BK=64, 8 waves (2M x 4N), wave tile 128x48.
// 4 phases per K-tile, counted-vmcnt pipeline (T3+T4+T5). Per wave per K-tile:
// 7 loads {q0: A(t+1)h0 x2, q1: A(t+1)h1 x2 + B(t+2)p0, q2: B(t+2)p1,
// q3: B(t+2)p2}, vmcnt(3) after q3 MFMA leaves exactly B(t+2)x3 in flight and
// drains A(t+1)+B(t+1). Prologue issues 10 (A0 x4, B0 x3, B1 x3) -> vmcnt(3).
// Clamped tail stages write dead regions; counts unchanged.
// LDS 112 KiB: 2 parities x (A 32K + B 24K), fragment-ordered (conflict-free),
// frag = 1 KiB = 16 rows x 32 k-half, addr = frag*512 + lane*8 (bf16 elems).
// ---------------------------------------------------------------------------
__device__ __forceinline__ void gemm256x192_core(const bf16* __restrict__ A,
                                                 const bf16* __restrict__ Bt,
                                                 int bm, int bn,
                                                 bf16* lds,
                                                 f32x4 acc[8][3])
{
    const int tid = threadIdx.x;
    const int wave = tid >> 6, lane = tid & 63, quad = lane >> 4, l16 = lane & 15;
    const int wr = wave >> 2, wc = wave & 3;

    // per-thread global src pointers (K-tile 0) and LDS element offsets
    const bf16* pA[4]; int dA[4];
#pragma unroll
    for (int h = 0; h < 2; ++h)
#pragma unroll
        for (int j = 0; j < 2; ++j) {
            const int f = h * 16 + j * 8 + wave;   // 32 A-frags
            pA[h * 2 + j] = A + (size_t)(bm * 256 + (f >> 1) * 16 + l16) * D_MODEL
                              + (f & 1) * 32 + quad * 8;
            dA[h * 2 + j] = f * 512 + lane * 8;
        }
    const bf16* pB[3]; int dB[3];
#pragma unroll
    for (int part = 0; part < 3; ++part) {
        const int f = part * 8 + wave;             // 24 B-frags
        pB[part] = Bt + (size_t)(bn * 192 + (f >> 1) * 16 + l16) * D_MODEL
                      + (f & 1) * 32 + quad * 8;
        dB[part] = 16384 + f * 512 + lane * 8;
    }

    auto stA = [&](int p, int kt, int h) {
#pragma unroll
        for (int j = 0; j < 2; ++j)
            async_copy16(pA[h * 2 + j] + kt * 64, lds + p * 28672 + dA[h * 2 + j]);
    };
    auto stB = [&](int p, int kt, int part) {
        async_copy16(pB[part] + kt * 64, lds + p * 28672 + dB[part]);
    };

    // prologue: A(0) x4, B(0) x3, B(1) x3 = 10 outstanding; drain to B(1) x3
    stA(0, 0, 0); stA(0, 0, 1);
    stB(0, 0, 0); stB(0, 0, 1); stB(0, 0, 2);
    stB(1, 1, 0); stB(1, 1, 1); stB(1, 1, 2);
    asm volatile("s_waitcnt vmcnt(3)" ::: "memory");
    __builtin_amdgcn_s_barrier();

    for (int t = 0; t < 32; ++t) {
        const int p = t & 1;
        const bf16* Ab = lds + p * 28672;
        const bf16* Bb = Ab + 16384;
        const int tn1 = (t + 1 < 31) ? t + 1 : 31;
        const int tn2 = (t + 2 < 31) ? t + 2 : 31;
        bf16x8 bfr[3][2];
#pragma unroll
        for (int q = 0; q < 4; ++q) {
            bf16x8 af[2][2];
#pragma unroll
            for (int mi = 0; mi < 2; ++mi)
#pragma unroll
                for (int kk = 0; kk < 2; ++kk) {
                    const int mt = wr * 8 + 2 * q + mi;
                    af[mi][kk] = *(const bf16x8*)(Ab + (mt * 2 + kk) * 512 + lane * 8);
                }
            if (q == 0) {
#pragma unroll
                for (int n = 0; n < 3; ++n)
#pragma unroll
                    for (int kk = 0; kk < 2; ++kk) {
                        const int nt = wc * 3 + n;
                        bfr[n][kk] = *(const bf16x8*)(Bb + (nt * 2 + kk) * 512 + lane * 8);
                    }
                stA(p ^ 1, tn1, 0);
            } else if (q == 1) {
                stA(p ^ 1, tn1, 1);
                stB(p, tn2, 0);
            } else if (q == 2) {
                stB(p, tn2, 1);
            } else {
                stB(p, tn2, 2);
            }

            __builtin_amdgcn_s_barrier();
            asm volatile("s_waitcnt lgkmcnt(0)" ::: "memory");
            __builtin_amdgcn_sched_barrier(0);
            __builtin_amdgcn_s_setprio(1);
#pragma unroll
            for (int mi = 0; mi < 2; ++mi)
#pragma unroll
                for (int n = 0; n < 3; ++n)
#pragma unroll
                    for (int kk = 0; kk < 2; ++kk)
                        acc[2 * q + mi][n] = __builtin_amdgcn_mfma_f32_16x16x32_bf16(
                            af[mi][kk], bfr[n][kk], acc[2 * q + mi][n], 0, 0, 0);
            __builtin_amdgcn_s_setprio(0);
            if (q == 3) asm volatile("s_waitcnt vmcnt(3)" ::: "memory");
            __builtin_amdgcn_s_barrier();
        }
    }
    asm volatile("s_waitcnt vmcnt(0)" ::: "memory");
}

// ---------------------------------------------------------------------------
// 128x256 bf16 GEMM core (round-4, harness-verified), BK=64, 8 waves
// (2M x 4N), wave tile 64x64. 2 phases/K-tile, counted vmcnt(4).
// LDS 96 KiB: 2 parities x (A 16K + B 32K), fragment-ordered.
// ---------------------------------------------------------------------------
__device__ __forceinline__ void gemm128x256_core(const bf16* __restrict__ A,
                                                 const bf16* __restrict__ Bt,
                                                 int bm, int bn,
                                                 bf16* lds,
                                                 f32x4 acc[4][4])
{
    const int tid = threadIdx.x;
    const int wave = tid >> 6, lane = tid & 63, quad = lane >> 4, l16 = lane & 15;
    const int wr = wave >> 2, wc = wave & 3;

    // precomputed per-thread src pointers (tile 0) and LDS element offsets
    const bf16* pA[2]; int dA[2];
#pragma unroll
    for (int j = 0; j < 2; ++j) {
        const int f = j * 8 + wave;            // 16 A-frags
        pA[j] = A + (size_t)(bm * 128 + (f >> 1) * 16 + l16) * D_MODEL + (f & 1) * 32 + quad * 8;
        dA[j] = f * 512 + lane * 8;
    }
    const bf16* pB[4]; int dB[4];
#pragma unroll
    for (int i = 0; i < 4; ++i) {
        const int f = (i >> 1) * 16 + (i & 1) * 8 + wave;   // 32 B-frags
        pB[i] = Bt + (size_t)(bn * 256 + (f >> 1) * 16 + l16) * D_MODEL + (f & 1) * 32 + quad * 8;
        dB[i] = f * 512 + lane * 8;
    }

    auto stA = [&](int p, int kt) {
#pragma unroll
        for (int j = 0; j < 2; ++j)
            async_copy16(pA[j] + kt * 64, lds + p * 24576 + dA[j]);
    };
    auto stB = [&](int p, int kt, int h) {
#pragma unroll
        for (int j = 0; j < 2; ++j)
            async_copy16(pB[h * 2 + j] + kt * 64, lds + p * 24576 + 8192 + dB[h * 2 + j]);
    };

    // prologue: A(0)x2, B(0)x4, B(1)x4 = 10 outstanding; drain to B(1)x4
    stA(0, 0); stB(0, 0, 0); stB(0, 0, 1); stB(1, 1, 0); stB(1, 1, 1);
    asm volatile("s_waitcnt vmcnt(4)" ::: "memory");
    __builtin_amdgcn_s_barrier();

    for (int t = 0; t < 32; ++t) {
        const int p = t & 1;
        const bf16* Ab = lds + p * 24576;
        const bf16* Bb = Ab + 8192;
        const int tn1 = (t + 1 < 31) ? t + 1 : 31;
        const int tn2 = (t + 2 < 31) ? t + 2 : 31;

        bf16x8 bfr[4][2], af[2][2];

        // ---- phase q0: A row-groups 0,1 x all B ----
#pragma unroll
        for (int mi = 0; mi < 2; ++mi)
#pragma unroll
            for (int kk = 0; kk < 2; ++kk)
                af[mi][kk] = *(const bf16x8*)(Ab + ((wr * 4 + mi) * 2 + kk) * 512 + lane * 8);
#pragma unroll
        for (int n = 0; n < 4; ++n)
#pragma unroll
            for (int kk = 0; kk < 2; ++kk)
                bfr[n][kk] = *(const bf16x8*)(Bb + ((wc * 4 + n) * 2 + kk) * 512 + lane * 8);
        stA(p ^ 1, tn1);
        __builtin_amdgcn_s_barrier();
        asm volatile("s_waitcnt lgkmcnt(0)" ::: "memory");
        __builtin_amdgcn_sched_barrier(0);
        __builtin_amdgcn_s_setprio(1);
#pragma unroll
        for (int mi = 0; mi < 2; ++mi)
#pragma unroll
            for (int n = 0; n < 4; ++n)
#pragma unroll
                for (int kk = 0; kk < 2; ++kk)
                    acc[mi][n] = __builtin_amdgcn_mfma_f32_16x16x32_bf16(
                        af[mi][kk], bfr[n][kk], acc[mi][n], 0, 0, 0);
        __builtin_amdgcn_s_setprio(0);
        __builtin_amdgcn_s_barrier();

        // ---- phase q1: A row-groups 2,3 x all B ----
#pragma unroll
        for (int mi = 0; mi < 2; ++mi)
#pragma unroll
            for (int kk = 0; kk < 2; ++kk)
                af[mi][kk] = *(const bf16x8*)(Ab + ((wr * 4 + 2 + mi) * 2 + kk) * 512 + lane * 8);
        stB(p, tn2, 0); stB(p, tn2, 1);
        __builtin_amdgcn_s_barrier();
        asm volatile("s_waitcnt lgkmcnt(0)" ::: "memory");
        __builtin_amdgcn_sched_barrier(0);
        __builtin_amdgcn_s_setprio(1);
#pragma unroll
        for (int mi = 0; mi < 2; ++mi)
#pragma unroll
            for (int n = 0; n < 4; ++n)
#pragma unroll
                for (int kk = 0; kk < 2; ++kk)
                    acc[2 + mi][n] = __builtin_amdgcn_mfma_f32_16x16x32_bf16(
                        af[mi][kk], bfr[n][kk], acc[2 + mi][n], 0, 0, 0);
        __builtin_amdgcn_s_setprio(0);
        asm volatile("s_waitcnt vmcnt(4)" ::: "memory");
        __builtin_amdgcn_s_barrier();
    }
    asm volatile("s_waitcnt vmcnt(0)" ::: "memory");
}

// ---------------------------------------------------------------------------
// Fused QKV projection GEMM: A [4096][2048] x WT rows 0..6143 ([q;k;v]).
// 256x192 tiles -> grid 512 blocks = exactly 2 full rounds (fill 1.0).
// z resolved per 16-col fragment. z==2 additionally emits the transposed
// bf16 V copy (vT [bh][d][s]) as aligned 8B stores -> transpose_v pass gone.
// ---------------------------------------------------------------------------
__global__ __launch_bounds__(512, 2)
void gemm_qkv_kernel(const bf16* __restrict__ A, const bf16* __restrict__ WT,
                     const float* __restrict__ bq, const float* __restrict__ bk,
                     const float* __restrict__ bv,
                     bf16* __restrict__ qout, float* __restrict__ kout,
                     bf16* __restrict__ kb16, float* __restrict__ vout,
                     bf16* __restrict__ vtout)
{
    __shared__ bf16 lds[57344];
    // XCD swizzle: 512 = 8 x 64; per XCD 64 tiles = 2 bm x 32 bn (A L2-resident)
    const int id = blockIdx.x;
    const int swz = (id & 7) * 64 + (id >> 3);
    const int bm = swz >> 5, bn = swz & 31;

    f32x4 acc[8][3] = {};
    gemm256x192_core(A, WT, bm, bn, lds, acc);

    const int tid = threadIdx.x;
    const int wave = tid >> 6, lane = tid & 63, quad = lane >> 4, l16 = lane & 15;
    const int wr = wave >> 2, wc = wave & 3;

#pragma unroll
    for (int a = 0; a < 8; ++a) {
#pragma unroll
        for (int n = 0; n < 3; ++n) {
            const int col0 = bn * 192 + wc * 48 + n * 16;   // 16-aligned
            const int z = col0 >> 11;                        // frag-uniform
            const float* __restrict__ bias = (z == 0) ? bq : (z == 1) ? bk : bv;
            const int nl = (col0 & 2047) + l16;
            const int h = nl >> 7, dh = nl & (DH - 1);
            const int m0 = bm * 256 + wr * 128 + a * 16 + quad * 4;
            const int b0 = m0 >> 11, s0 = m0 & (SEQ - 1);
            bf16x4 vt4;
#pragma unroll
            for (int r = 0; r < 4; ++r) {
                int m = m0 + r;
                float val = acc[a][n][r] + bias[nl];
                int b = m >> 11, s = m & (SEQ - 1);
                size_t off = ((size_t)(b * NHEADS + h) * SEQ + s) * DH + dh;
                if (z == 0) {
                    qout[off] = (bf16)val;
                } else if (z == 1) {
                    kout[off] = val;
                    kb16[off] = (bf16)val;
                } else {
                    vout[off] = val;
                    vt4[r] = (bf16)val;
                }
            }
            if (z == 2) {
                // vT [bh][dh][s]: 4 consecutive s -> one aligned 8B store
                size_t voff = ((size_t)(b0 * NHEADS + h) * DH + dh) * SEQ + s0;
                *(bf16x4*)&vtout[voff] = vt4;
            }
        }
    }
}

// ---------------------------------------------------------------------------
// Output projection GEMM: attn_out = ctx @ Wo + bo (fp32 out [4096][2048]).
// 128x256 tiles -> 256 blocks (32 bm x 8 bn) = exactly 1 block/CU (fill 1.0).
// ---------------------------------------------------------------------------
__global__ __launch_bounds__(512, 2)
void gemm_out_kernel(const bf16* __restrict__ A, const bf16* __restrict__ Bt,
                     const float* __restrict__ bias, float* __restrict__ out)
{
    __shared__ bf16 lds[49152];
    const int id = blockIdx.x;
    const int swz = (id & 7) * 32 + (id >> 3);   // 256 = 8 x 32
    const int bm = swz & 31, bn = swz >> 5;

    f32x4 acc[4][4] = {};
    gemm128x256_core(A, Bt, bm, bn, lds, acc);

    const int tid = threadIdx.x;
    const int wave = tid >> 6, lane = tid & 63, quad = lane >> 4, l16 = lane & 15;
    const int wr = wave >> 2, wc = wave & 3;

#pragma unroll
    for (int a = 0; a < 4; ++a) {
#pragma unroll
        for (int n = 0; n < 4; ++n) {
#pragma unroll
            for (int r = 0; r < 4; ++r) {
                int m  = bm * 128 + wr * 64 + a * 16 + quad * 4 + r;
                int nn = bn * 256 + wc * 64 + n * 16 + l16;
                out[(size_t)m * D_MODEL + nn] = acc[a][n][r] + bias[nn];
            }
        }
    }
}

// ---------------------------------------------------------------------------
// Flash attention (causal). One block per (128-row q tile, bh): 8 waves.
// Q,K bf16 [bh][s][128]; Vt bf16 [bh][128][s]; ctx bf16 [b][s][h*128+d].
// v3: QBLK 64 -> 128 (8 waves, 512 threads). K/V tile staged once per 128
// q-rows instead of 64 -> staging bytes, barriers, loop overhead per unit
// MFMA all halve (528 -> 272 tile-stages per bh). LDS 48 KB (K 16 + V 16 +
// P 16), 512 blocks all co-resident at 2 blocks/CU (16 waves/CU).
// Mask is unconditional kcol > qrow (fully-masked half-tiles are numerically
// safe: mx=-inf -> alpha=1, rs=0). Balanced remap: CU c gets ids {c, c+256}
// with qb = 15-g / g -> uniform 34 iterations per CU.
// ---------------------------------------------------------------------------
__global__ __launch_bounds__(512, 4)
void attn_kernel(const bf16* __restrict__ Q, const bf16* __restrict__ K,
                 const bf16* __restrict__ Vt, bf16* __restrict__ ctx)
{
    const int id = blockIdx.x;       // 512 = 32 bh x 16 qb
    const int bh = id & 31;
    const int g  = (id >> 5) & 7;
    const int qb = (id < 256) ? (15 - g) : g;

    const int tid = threadIdx.x;
    const int wave = tid >> 6, lane = tid & 63, quad = lane >> 4, l16 = lane & 15;

    __shared__ bf16 Ks[64 * 128];    // 16 KB, row stride 256 B
    __shared__ bf16 VsT[128 * 64];   // 16 KB, row stride 128 B ([d][key])
    __shared__ bf16 Ps[8 * 16 * 64]; // 16 KB, per-wave [16][64], stride 128 B
    char* const ksb = (char*)Ks;
    char* const vsb = (char*)VsT;
    char* const psb = (char*)Ps + wave * 2048;

    // Q fragments straight from global (one-time, row-strided 16B loads)
    const bf16* qsrc = Q + ((size_t)bh * SEQ + (size_t)qb * 128 + wave * 16 + l16) * DH;
    bf16x8 qf[4];
#pragma unroll
    for (int dd = 0; dd < 4; ++dd)
        qf[dd] = *(const bf16x8*)&qsrc[dd * 32 + quad * 8];

    f32x4 o[8] = {};
    float m_i[4], l_i[4];
#pragma unroll
    for (int r = 0; r < 4; ++r) { m_i[r] = -INFINITY; l_i[r] = 0.f; }

    const float scale = 0.08838834764831845f;  // 1/sqrt(128)
    const bf16* ksrc0 = K + (size_t)bh * SEQ * DH;
    const bf16* vsrc0 = Vt + (size_t)bh * DH * SEQ;
    const int kbmax = 2 * qb + 1;

    for (int kb = 0; kb <= kbmax; ++kb) {
        __syncthreads();   // previous iteration's K/V reads done

        // stage K tile (64 x 128): linear LDS dest, pre-swizzled global src
        {
            const char* kg = (const char*)(ksrc0 + (size_t)(kb * 64) * DH);
#pragma unroll
            for (int i = 0; i < 2; ++i) {
                int seg = i * 8 + wave;            // 16 segs x 1 KB
                int row = seg * 4 + (lane >> 4);   // 0..63
                int colb = (lane & 15) * 16;       // physical col byte
                const char* src = kg + row * 256 + (colb ^ ((row & 7) << 4));
                async_copy16((const bf16*)src, (bf16*)(ksb + seg * 1024));
            }
            // stage Vt tile (128 d-rows x 64 keys)
            const char* vg = (const char*)(vsrc0 + kb * 64);
#pragma unroll
            for (int i = 0; i < 2; ++i) {
                int seg = i * 8 + wave;
                int d = seg * 8 + (lane >> 3);     // 0..127
                int colb = (lane & 7) * 16;
                const char* src = vg + (size_t)d * (SEQ * 2) + (colb ^ ((d & 7) << 4));
                async_copy16((const bf16*)src, (bf16*)(vsb + seg * 1024));
            }
        }
        __syncthreads();

        // S = Q K^T (16 rows x 64 keys per wave)
        float pvals[4][4];
#pragma unroll
        for (int t = 0; t < 4; ++t) {
            f32x4 s = {};
            const int row = t * 16 + l16;
            const int swz = (row & 7) << 4;
#pragma unroll
            for (int dd = 0; dd < 4; ++dd) {
                bf16x8 b = *(const bf16x8*)(ksb + row * 256 + ((dd * 64 + quad * 16) ^ swz));
                s = __builtin_amdgcn_mfma_f32_16x16x32_bf16(qf[dd], b, s, 0, 0, 0);
            }
#pragma unroll
            for (int r = 0; r < 4; ++r) pvals[t][r] = s[r];
        }

#pragma unroll
        for (int r = 0; r < 4; ++r) {
            int qrow = qb * 128 + wave * 16 + quad * 4 + r;
            float mx = -INFINITY;
#pragma unroll
            for (int t = 0; t < 4; ++t) {
                float s = pvals[t][r] * scale;
                int kcol = kb * 64 + t * 16 + l16;
                if (kcol > qrow) s = -INFINITY;
                pvals[t][r] = s;
                mx = fmaxf(mx, s);
            }
#pragma unroll
            for (int off = 1; off < 16; off <<= 1)
                mx = fmaxf(mx, __shfl_xor(mx, off, 64));
            float mnew = fmaxf(m_i[r], mx);
            float alpha = __expf(m_i[r] - mnew);
            m_i[r] = mnew;
            float rs = 0.f;
#pragma unroll
            for (int t = 0; t < 4; ++t) {
                float pexp = __expf(pvals[t][r] - mnew);
                pvals[t][r] = pexp;
                rs += pexp;
            }
#pragma unroll
            for (int off = 1; off < 16; off <<= 1)
                rs += __shfl_xor(rs, off, 64);
            l_i[r] = l_i[r] * alpha + rs;
#pragma unroll
            for (int dt = 0; dt < 8; ++dt) o[dt][r] *= alpha;
        }

        // P -> LDS (C-layout -> A-layout), wave-local, swizzled
#pragma unroll
        for (int t = 0; t < 4; ++t)
#pragma unroll
            for (int r = 0; r < 4; ++r) {
                int row = quad * 4 + r;
                *(bf16*)(psb + row * 128 + (((t * 16 + l16) * 2) ^ ((row & 7) << 4))) =
                    (bf16)pvals[t][r];
            }

        // O += P @ V  (swizzled b-fragments from VsT)
        bf16x8 pa[2];
#pragma unroll
        for (int kk2 = 0; kk2 < 2; ++kk2)
            pa[kk2] = *(const bf16x8*)(psb + l16 * 128 +
                                       ((kk2 * 64 + quad * 16) ^ ((l16 & 7) << 4)));
#pragma unroll
        for (int dt = 0; dt < 8; ++dt) {
            const int row = dt * 16 + l16;
            const int swz = (row & 7) << 4;
#pragma unroll
            for (int kk2 = 0; kk2 < 2; ++kk2) {
                bf16x8 b = *(const bf16x8*)(vsb + row * 128 + ((kk2 * 64 + quad * 16) ^ swz));
                o[dt] = __builtin_amdgcn_mfma_f32_16x16x32_bf16(pa[kk2], b, o[dt], 0, 0, 0);
            }
        }
    }

    // epilogue
    const int b = bh >> 4, h = bh & (NHEADS - 1);
    float inv_l[4];
#pragma unroll
    for (int r = 0; r < 4; ++r) inv_l[r] = 1.0f / l_i[r];
#pragma unroll
    for (int dt = 0; dt < 8; ++dt) {
#pragma unroll
        for (int r = 0; r < 4; ++r) {
            int s = qb * 128 + wave * 16 + quad * 4 + r;
            int d = dt * 16 + l16;
            ctx[((size_t)(b * SEQ + s)) * D_MODEL + h * DH + d] = (bf16)(o[dt][r] * inv_l[r]);
        }
    }
}

// ---------------------------------------------------------------------------
// Residual + LayerNorm: one block per row
// ---------------------------------------------------------------------------
__global__ __launch_bounds__(256)
void ln_kernel(const float* __restrict__ attn, const float* __restrict__ x,
               const float* __restrict__ gamma, const float* __restrict__ beta,
               float* __restrict__ ln)
{
    const int row = blockIdx.x;
    const int tid = threadIdx.x;
    const int wave = tid >> 6, lane = tid & 63;
    const float* a  = attn + (size_t)row * D_MODEL;
    const float* xr = x    + (size_t)row * D_MODEL;

    float4 y4[2];
    float sum = 0.f, sumsq = 0.f;
#pragma unroll
    for (int i = 0; i < 2; ++i) {
        int c = (tid + i * 256) * 4;
        float4 av = *(const float4*)&a[c];
        float4 xv = *(const float4*)&xr[c];
        float4 y;
        y.x = av.x + xv.x; y.y = av.y + xv.y; y.z = av.z + xv.z; y.w = av.w + xv.w;
        y4[i] = y;
        sum   += y.x + y.y + y.z + y.w;
        sumsq += y.x * y.x + y.y * y.y + y.z * y.z + y.w * y.w;
    }
#pragma unroll
    for (int off = 1; off < 64; off <<= 1) {
        sum   += __shfl_xor(sum, off, 64);
        sumsq += __shfl_xor(sumsq, off, 64);
    }
    __shared__ float rsum[4], rsumsq[4];
    if (lane == 0) { rsum[wave] = sum; rsumsq[wave] = sumsq; }
    __syncthreads();
    float tot = 0.f, tot2 = 0.f;
#pragma unroll
    for (int i = 0; i < 4; ++i) { tot += rsum[i]; tot2 += rsumsq[i]; }
    const float mu  = tot * (1.0f / D_MODEL);
    const float var = tot2 * (1.0f / D_MODEL) - mu * mu;
    const float rstd = rsqrtf(var + 1e-5f);

#pragma unroll
    for (int i = 0; i < 2; ++i) {
        int c = (tid + i * 256) * 4;
        float4 gv = *(const float4*)&gamma[c];
        float4 bv = *(const float4*)&beta[c];
        float4 y = y4[i];
        float4 r;
        r.x = gv.x * (y.x - mu) * rstd + bv.x;
        r.y = gv.y * (y.y - mu) * rstd + bv.y;
        r.z = gv.z * (y.z - mu) * rstd + bv.z;
        r.w = gv.w * (y.w - mu) * rstd + bv.w;
        *(float4*)&ln[(size_t)row * D_MODEL + c] = r;
    }
}

// ---------------------------------------------------------------------------
extern "C" void kernel_launch(void* const* d_in, const int* in_sizes, int n_in,
                              void* d_out, int out_size, void* d_ws, size_t ws_size,
                              hipStream_t stream)
{
    const float* x     = (const float*)d_in[0];
    const float* Wq    = (const float*)d_in[1];
    const float* bq    = (const float*)d_in[2];
    const float* Wk    = (const float*)d_in[3];
    const float* bk    = (const float*)d_in[4];
    const float* Wv    = (const float*)d_in[5];
    const float* bv    = (const float*)d_in[6];
    const float* Wo    = (const float*)d_in[7];
    const float* bo    = (const float*)d_in[8];
    const float* gamma = (const float*)d_in[9];
    const float* beta  = (const float*)d_in[10];

    float* out      = (float*)d_out;
    float* ln       = out;                 // [B,S,D]
    float* attn_out = out + 8388608;       // [B,S,D]
    float* kout     = out + 16777216;      // [B,H,S,Dh]
    float* vout     = out + 25165824;      // [B,H,S,Dh]

    // workspace layout (bf16 elements)
    bf16* wsb  = (bf16*)d_ws;
    bf16* xb   = wsb;                        // [4096][2048]            8M
    bf16* WT   = wsb + 8388608;              // 4x [2048][2048] (q,k,v,o) 16M
    bf16* qws  = wsb + 25165824;             // [bh][s][128]            8M
    bf16* kb16 = wsb + 33554432;             // [bh][s][128]            8M
    bf16* vT   = wsb + 41943040;             // [bh][128][s]            8M
    bf16* ctx  = wsb + 50331648;             // [4096][2048]            8M

    convert_x_kernel<<<8192, 256, 0, stream>>>(x, xb);
    transpose_w_kernel<<<dim3(32, 32, 4), 256, 0, stream>>>(Wq, Wk, Wv, Wo, WT);
    gemm_qkv_kernel<<<dim3(512), 512, 0, stream>>>(xb, WT, bq, bk, bv,
                                                    qws, kout, kb16, vout, vT);
    attn_kernel<<<dim3(512), 512, 0, stream>>>(qws, kb16, vT, ctx);
    gemm_out_kernel<<<dim3(256), 512, 0, stream>>>(ctx, WT + 3 * (size_t)(D_MODEL * D_MODEL),
                                                    bo, attn_out);
    ln_kernel<<<4096, 256, 0, stream>>>(attn_out, x, gamma, beta, ln);
}